// Round 4
// baseline (251.308 us; speedup 1.0000x reference)
//
#include <hip/hip_runtime.h>
#include <math.h>

#define TOTAL   8192
#define GENES   5000
#define NDS     64          // points per cloud
#define NB      128         // TOTAL / NDS
#define NSHARED 128
#define KC      64          // K-chunk staged in LDS

// ws layout (floats): [0]=gene acc, [1]=cell acc, grams start at GRAM_OFF
#define GRAM_OFF 64

typedef __attribute__((ext_vector_type(8)))  short          short8;
typedef __attribute__((ext_vector_type(4)))  unsigned short ushort4v;
typedef __attribute__((ext_vector_type(16))) float          f32x16;

static __device__ inline unsigned short f2bf(float f) {
    unsigned int u = __builtin_bit_cast(unsigned int, f);
    unsigned int r = (u + 0x7fffu + ((u >> 16) & 1u)) >> 16;   // RNE
    return (unsigned short)r;
}
static __device__ inline float bf2f(unsigned short h) {
    unsigned int u = ((unsigned int)h) << 16;
    return __builtin_bit_cast(float, u);
}

__global__ __launch_bounds__(64) void k_zero(float* ws) {
    ws[threadIdx.x] = 0.0f;
}

// ---------------------------------------------------------------------------
// K1: partial Gram matrices per (batch, K-slice) via bf16 hi/lo split MFMA.
// Gxy = XhYh + XhYl + XlYh  (lo*lo dropped, ~3e-4 abs on O(1e4) entries)
// grams[(b*splitD + c)][m][64*64], m: 0=xy, 1=xx, 2=yy
// Round-2 structure (no reg-prefetch: round-3 showed it spills -> scratch
// traffic). Latency hidden via occupancy (splitD=8 -> 4 blocks/CU).
// ---------------------------------------------------------------------------
__global__ __launch_bounds__(256) void k_gene_gram_mfma(const float* __restrict__ X,
                                                        const float* __restrict__ Y,
                                                        float* __restrict__ grams,
                                                        int splitD, int Dper) {
    const int blk = blockIdx.x;
    const int b = blk / splitD, c = blk % splitD;
    const int d0 = c * Dper;
    const int d1 = min(GENES, d0 + Dper);

    const float* __restrict__ xb = X + (size_t)b * NDS * GENES;
    const float* __restrict__ yb = Y + (size_t)b * NDS * GENES;

    // [m][k] bf16 tiles, element-XOR swizzle  k ^ ((m&7)<<3)  (16B granularity)
    __shared__ __align__(16) unsigned short sXh[NDS * KC], sXl[NDS * KC];
    __shared__ __align__(16) unsigned short sYh[NDS * KC], sYl[NDS * KC];

    const int t    = threadIdx.x;
    const int lane = t & 63;
    const int w    = t >> 6;               // wave 0..3
    const int qr   = w >> 1, qc = w & 1;   // 32x32 output quadrant
    const int lm   = lane & 31;
    const int kh   = (lane >> 5) << 3;     // k-half offset (consistent A/B: cancels)

    const int mr = (qr << 5) + lm;         // A-side row
    const int mc = (qc << 5) + lm;         // B-side row (Gram col)

    f32x16 axy = {0,0,0,0,0,0,0,0,0,0,0,0,0,0,0,0};
    f32x16 axx = {0,0,0,0,0,0,0,0,0,0,0,0,0,0,0,0};
    f32x16 ayy = {0,0,0,0,0,0,0,0,0,0,0,0,0,0,0,0};

    for (int dd0 = d0; dd0 < d1; dd0 += KC) {
        __syncthreads();   // previous chunk fully consumed
        // ---- stage: coalesced float4 loads -> hi/lo bf16, swizzled LDS ----
#pragma unroll
        for (int it = 0; it < 4; ++it) {
            const int c4 = t & 15;                 // float4 column
            const int m  = (t >> 4) + (it << 4);   // row 0..63
            const int d  = dd0 + (c4 << 2);
            float vx[4] = {0.f, 0.f, 0.f, 0.f};
            float vy[4] = {0.f, 0.f, 0.f, 0.f};
            if (d + 3 < d1) {
                const float4 fx = *(const float4*)(xb + (size_t)m * GENES + d);
                const float4 fy = *(const float4*)(yb + (size_t)m * GENES + d);
                vx[0]=fx.x; vx[1]=fx.y; vx[2]=fx.z; vx[3]=fx.w;
                vy[0]=fy.x; vy[1]=fy.y; vy[2]=fy.z; vy[3]=fy.w;
            } else if (d < d1) {
                for (int q = 0; q < d1 - d; ++q) {
                    vx[q] = xb[(size_t)m * GENES + d + q];
                    vy[q] = yb[(size_t)m * GENES + d + q];
                }
            }
            ushort4v xh, xl, yh, yl;
#pragma unroll
            for (int q = 0; q < 4; ++q) {
                const unsigned short h = f2bf(vx[q]);
                xh[q] = h; xl[q] = f2bf(vx[q] - bf2f(h));
                const unsigned short g = f2bf(vy[q]);
                yh[q] = g; yl[q] = f2bf(vy[q] - bf2f(g));
            }
            const int e = m * KC + (((c4 << 2)) ^ ((m & 7) << 3));
            *(ushort4v*)&sXh[e] = xh;
            *(ushort4v*)&sXl[e] = xl;
            *(ushort4v*)&sYh[e] = yh;
            *(ushort4v*)&sYl[e] = yl;
        }
        __syncthreads();
        // ---- compute: 4 K=16 steps, 9 MFMAs each into 3 accumulators ----
#pragma unroll
        for (int ks = 0; ks < 4; ++ks) {
            const int kb = (ks << 4) + kh;
            const int er = mr * KC + (kb ^ ((mr & 7) << 3));
            const int ec = mc * KC + (kb ^ ((mc & 7) << 3));
            const short8 xhr = *(const short8*)&sXh[er];
            const short8 xlr = *(const short8*)&sXl[er];
            const short8 yhr = *(const short8*)&sYh[er];
            const short8 ylr = *(const short8*)&sYl[er];
            const short8 xhc = *(const short8*)&sXh[ec];
            const short8 xlc = *(const short8*)&sXl[ec];
            const short8 yhc = *(const short8*)&sYh[ec];
            const short8 ylc = *(const short8*)&sYl[ec];
            axy = __builtin_amdgcn_mfma_f32_32x32x16_bf16(xhr, yhc, axy, 0, 0, 0);
            axx = __builtin_amdgcn_mfma_f32_32x32x16_bf16(xhr, xhc, axx, 0, 0, 0);
            ayy = __builtin_amdgcn_mfma_f32_32x32x16_bf16(yhr, yhc, ayy, 0, 0, 0);
            axy = __builtin_amdgcn_mfma_f32_32x32x16_bf16(xhr, ylc, axy, 0, 0, 0);
            axx = __builtin_amdgcn_mfma_f32_32x32x16_bf16(xhr, xlc, axx, 0, 0, 0);
            ayy = __builtin_amdgcn_mfma_f32_32x32x16_bf16(yhr, ylc, ayy, 0, 0, 0);
            axy = __builtin_amdgcn_mfma_f32_32x32x16_bf16(xlr, yhc, axy, 0, 0, 0);
            axx = __builtin_amdgcn_mfma_f32_32x32x16_bf16(xlr, xhc, axx, 0, 0, 0);
            ayy = __builtin_amdgcn_mfma_f32_32x32x16_bf16(ylr, yhc, ayy, 0, 0, 0);
        }
    }

    // ---- writeout: verified 32x32 C/D layout: col=lane&31,
    //      row=(reg&3)+8*(reg>>2)+4*(lane>>5) ----
    float* g = grams + (size_t)(b * splitD + c) * 3 * 4096;
    const int col = (qc << 5) + lm;
#pragma unroll
    for (int r = 0; r < 16; ++r) {
        const int row = (qr << 5) + (r & 3) + ((r >> 2) << 3) + ((lane >> 5) << 2);
        g[0 * 4096 + row * 64 + col] = axy[r];
        g[1 * 4096 + row * 64 + col] = axx[r];
        g[2 * 4096 + row * 64 + col] = ayy[r];
    }
}

// ---------------------------------------------------------------------------
// K2: per batch — reduce Gram partials, distances, mean, accumulate.
// ---------------------------------------------------------------------------
__global__ __launch_bounds__(256) void k_gene_dist(const float* __restrict__ grams,
                                                   float* __restrict__ acc,
                                                   int splitD) {
    const int b = blockIdx.x, t = threadIdx.x;
    __shared__ __align__(16) float G[3 * 4096];   // 48 KB
    __shared__ float red[4];

    for (int m = 0; m < 3; ++m) {
#pragma unroll
        for (int k = 0; k < 16; ++k) {
            const int e = t + 256 * k;
            float s = 0.f;
            for (int c = 0; c < splitD; ++c)
                s += grams[((size_t)(b * splitD + c) * 3 + m) * 4096 + e];
            G[m * 4096 + e] = s;
        }
    }
    __syncthreads();

    float local = 0.f;
#pragma unroll
    for (int k = 0; k < 16; ++k) {
        const int e = t + 256 * k;
        const int i = e >> 6, j = e & 63;
        const float gxy = G[e];
        const float gxx = G[4096 + e];
        const float gyy = G[8192 + e];
        const float nxi = G[4096 + i * 65], nxj = G[4096 + j * 65];
        const float nyi = G[8192 + i * 65], nyj = G[8192 + j * 65];
        const float dxy = sqrtf(fmaxf(nxi + nyj - 2.f * gxy, 0.f));
        const float dxx = sqrtf(fmaxf(nxi + nxj - 2.f * gxx, 0.f));
        const float dyy = sqrtf(fmaxf(nyi + nyj - 2.f * gyy, 0.f));
        local += dxy - 0.5f * (dxx + dyy);
    }
#pragma unroll
    for (int off = 32; off; off >>= 1) local += __shfl_down(local, off);
    if ((t & 63) == 0) red[t >> 6] = local;
    __syncthreads();
    if (t == 0) {
        const float bl = red[0] + red[1] + red[2] + red[3];
        atomicAdd(acc, bl * (1.0f / (4096.0f * (float)NB)));
    }
}

// ---------------------------------------------------------------------------
// K3: cell-level — one block per shared gene s. Clouds: 64 points x 128 dims.
// (Column loads are uncoalesced but L2/L3-resident: round-3's transpose
// variant measured equal, so keep the simpler form.)
// ---------------------------------------------------------------------------
__global__ __launch_bounds__(256) void k_cell(const float* __restrict__ X,
                                              const float* __restrict__ Y,
                                              float* __restrict__ acc) {
    const int s   = blockIdx.x;
    const int col = GENES - NSHARED + s;
    const int t   = threadIdx.x;

    // cx tile [b][n] at [0..8191], cy at [8192..16383]; reused for Grams after
    __shared__ __align__(16) float lds[16384];    // 64 KB

#pragma unroll
    for (int k = 0; k < 32; ++k) {
        const int idx = t + 256 * k;              // = b*64 + n, 0..8191
        lds[idx]        = X[(size_t)idx * GENES + col];
        lds[8192 + idx] = Y[(size_t)idx * GENES + col];
    }
    __syncthreads();

    const int ti = t & 15, tj = t >> 4;
    const int i0 = ti << 2, j0 = tj << 2;
    float axy[4][4] = {{0}}, axx[4][4] = {{0}}, ayy[4][4] = {{0}};

#pragma unroll 4
    for (int bb = 0; bb < NB; ++bb) {
        const float4 xi4 = *(const float4*)(lds + bb * 64 + i0);
        const float4 xj4 = *(const float4*)(lds + bb * 64 + j0);
        const float4 yi4 = *(const float4*)(lds + 8192 + bb * 64 + i0);
        const float4 yj4 = *(const float4*)(lds + 8192 + bb * 64 + j0);
        const float* xi = &xi4.x;
        const float* xj = &xj4.x;
        const float* yi = &yi4.x;
        const float* yj = &yj4.x;
#pragma unroll
        for (int ii = 0; ii < 4; ++ii) {
#pragma unroll
            for (int jj = 0; jj < 4; ++jj) {
                axy[ii][jj] = fmaf(xi[ii], yj[jj], axy[ii][jj]);
                axx[ii][jj] = fmaf(xi[ii], xj[jj], axx[ii][jj]);
                ayy[ii][jj] = fmaf(yi[ii], yj[jj], ayy[ii][jj]);
            }
        }
    }
    __syncthreads();
    // write Grams into lds[0..12287] (tiles no longer needed)
#pragma unroll
    for (int ii = 0; ii < 4; ++ii) {
        float4 v;
        v.x = axy[ii][0]; v.y = axy[ii][1]; v.z = axy[ii][2]; v.w = axy[ii][3];
        *(float4*)(lds + 0 * 4096 + (i0 + ii) * 64 + j0) = v;
        v.x = axx[ii][0]; v.y = axx[ii][1]; v.z = axx[ii][2]; v.w = axx[ii][3];
        *(float4*)(lds + 1 * 4096 + (i0 + ii) * 64 + j0) = v;
        v.x = ayy[ii][0]; v.y = ayy[ii][1]; v.z = ayy[ii][2]; v.w = ayy[ii][3];
        *(float4*)(lds + 2 * 4096 + (i0 + ii) * 64 + j0) = v;
    }
    __syncthreads();

    float local = 0.f;
#pragma unroll
    for (int k = 0; k < 16; ++k) {
        const int e = t + 256 * k;
        const int i = e >> 6, j = e & 63;
        const float gxy = lds[e];
        const float gxx = lds[4096 + e];
        const float gyy = lds[8192 + e];
        const float nxi = lds[4096 + i * 65], nxj = lds[4096 + j * 65];
        const float nyi = lds[8192 + i * 65], nyj = lds[8192 + j * 65];
        const float dxy = sqrtf(fmaxf(nxi + nyj - 2.f * gxy, 0.f));
        const float dxx = sqrtf(fmaxf(nxi + nxj - 2.f * gxx, 0.f));
        const float dyy = sqrtf(fmaxf(nyi + nyj - 2.f * gyy, 0.f));
        local += dxy - 0.5f * (dxx + dyy);
    }
#pragma unroll
    for (int off = 32; off; off >>= 1) local += __shfl_down(local, off);
    __syncthreads();                 // done reading lds as Grams
    if ((t & 63) == 0) lds[t >> 6] = local;
    __syncthreads();
    if (t == 0) {
        const float bl = lds[0] + lds[1] + lds[2] + lds[3];
        atomicAdd(acc, bl * (1.0f / (4096.0f * (float)NSHARED)));
    }
}

__global__ void k_final(const float* __restrict__ acc, float* __restrict__ out) {
    out[0] = acc[0] + acc[1];
}

extern "C" void kernel_launch(void* const* d_in, const int* in_sizes, int n_in,
                              void* d_out, int out_size, void* d_ws, size_t ws_size,
                              hipStream_t stream) {
    const float* X = (const float*)d_in[0];
    const float* Y = (const float*)d_in[1];
    float* out = (float*)d_out;
    float* ws  = (float*)d_ws;

    // pick largest splitD (K-slices per batch) whose partial-Gram buffer fits
    // in ws. 8 -> 1024 blocks = 4 blocks/CU (occupancy lever, round 4).
    int splitD = 1;
    const int cand[4] = {8, 6, 4, 2};
    for (int i = 0; i < 4; ++i) {
        if (((size_t)GRAM_OFF + (size_t)cand[i] * NB * 3 * 4096) * sizeof(float)
            <= ws_size) { splitD = cand[i]; break; }
    }
    const int chunks = (GENES + KC - 1) / KC;            // 79
    const int cper   = (chunks + splitD - 1) / splitD;   // chunks per slice
    const int Dper   = cper * KC;                        // multiple of KC

    float* acc   = ws;
    float* grams = ws + GRAM_OFF;

    hipLaunchKernelGGL(k_zero,           dim3(1),           dim3(64),  0, stream, acc);
    hipLaunchKernelGGL(k_gene_gram_mfma, dim3(NB * splitD), dim3(256), 0, stream,
                       X, Y, grams, splitD, Dper);
    hipLaunchKernelGGL(k_gene_dist,      dim3(NB),          dim3(256), 0, stream,
                       grams, acc + 0, splitD);
    hipLaunchKernelGGL(k_cell,           dim3(NSHARED),     dim3(256), 0, stream,
                       X, Y, acc + 1);
    hipLaunchKernelGGL(k_final,          dim3(1),           dim3(1),   0, stream, acc, out);
}

// Round 5
// 225.257 us; speedup vs baseline: 1.1156x; 1.1156x over previous
//
#include <hip/hip_runtime.h>
#include <math.h>

#define TOTAL   8192
#define GENES   5000
#define NDS     64          // points per cloud
#define NB      128         // TOTAL / NDS
#define NSHARED 128
#define KC      64          // K-chunk staged in LDS

// ws layout (floats): [0]=gene acc, [1]=cell acc, grams start at GRAM_OFF
#define GRAM_OFF 64

typedef __attribute__((ext_vector_type(8)))  short          short8;
typedef __attribute__((ext_vector_type(4)))  unsigned short ushort4v;
typedef __attribute__((ext_vector_type(16))) float          f32x16;

static __device__ inline unsigned short f2bf(float f) {
    unsigned int u = __builtin_bit_cast(unsigned int, f);
    unsigned int r = (u + 0x7fffu + ((u >> 16) & 1u)) >> 16;   // RNE
    return (unsigned short)r;
}
static __device__ inline float bf2f(unsigned short h) {
    unsigned int u = ((unsigned int)h) << 16;
    return __builtin_bit_cast(float, u);
}

__global__ __launch_bounds__(64) void k_zero(float* ws) {
    ws[threadIdx.x] = 0.0f;
}

// ---------------------------------------------------------------------------
// K1: partial Gram matrices per (batch, K-slice) via bf16 hi/lo split MFMA.
// T14 async-stage: double-buffered LDS, ONE barrier per chunk, global loads
// issued into registers BEFORE the barrier so HBM latency hides under MFMA.
// grams[(b*splitD + c)][m][64*64], m: 0=xy, 1=xx, 2=yy
// ---------------------------------------------------------------------------
__global__ __launch_bounds__(256) void k_gene_gram_mfma(const float* __restrict__ X,
                                                        const float* __restrict__ Y,
                                                        float* __restrict__ grams,
                                                        int splitD, int Dper) {
    const int blk = blockIdx.x;
    const int b = blk / splitD, c = blk % splitD;
    const int d0 = c * Dper;
    const int d1 = min(GENES, d0 + Dper);

    const float* __restrict__ xb = X + (size_t)b * NDS * GENES;
    const float* __restrict__ yb = Y + (size_t)b * NDS * GENES;

    // [buf][m][k] bf16 tiles, element-XOR swizzle k ^ ((m&7)<<3) (16B blocks)
    __shared__ __align__(16) unsigned short sXh[2 * NDS * KC], sXl[2 * NDS * KC];
    __shared__ __align__(16) unsigned short sYh[2 * NDS * KC], sYl[2 * NDS * KC];

    const int t    = threadIdx.x;
    const int lane = t & 63;
    const int w    = t >> 6;               // wave 0..3
    const int qr   = w >> 1, qc = w & 1;   // 32x32 output quadrant
    const int lm   = lane & 31;
    const int kh   = (lane >> 5) << 3;     // k-half offset (same for A/B: cancels)

    const int mr = (qr << 5) + lm;         // A-side row
    const int mc = (qc << 5) + lm;         // B-side row (Gram col)

    // staging-thread geometry
    const int c4  = t & 15;                // float4 column within chunk
    const int mrw = t >> 4;                // base row (16 rows per iteration)
    const int dcol = c4 << 2;

    f32x16 axy = {0,0,0,0,0,0,0,0,0,0,0,0,0,0,0,0};
    f32x16 axx = {0,0,0,0,0,0,0,0,0,0,0,0,0,0,0,0};
    f32x16 ayy = {0,0,0,0,0,0,0,0,0,0,0,0,0,0,0,0};

    float4 rx0, rx1, rx2, rx3, ry0, ry1, ry2, ry3;   // named: no array indexing

    // ---- issue chunk loads into registers (guarded tail) ----
    auto issue_loads = [&](int dd0) {
        const int d = dd0 + dcol;
        if (d + 3 < d1) {
            const float* px = xb + (size_t)mrw * GENES + d;
            const float* py = yb + (size_t)mrw * GENES + d;
            rx0 = *(const float4*)(px);
            ry0 = *(const float4*)(py);
            rx1 = *(const float4*)(px + 16 * GENES);
            ry1 = *(const float4*)(py + 16 * GENES);
            rx2 = *(const float4*)(px + 32 * GENES);
            ry2 = *(const float4*)(py + 32 * GENES);
            rx3 = *(const float4*)(px + 48 * GENES);
            ry3 = *(const float4*)(py + 48 * GENES);
        } else {
            float4 z = {0.f, 0.f, 0.f, 0.f};
            rx0 = rx1 = rx2 = rx3 = z;
            ry0 = ry1 = ry2 = ry3 = z;
            if (d < d1) {
                const int nq = d1 - d;
                float* dstx[4] = {&rx0.x, &rx1.x, &rx2.x, &rx3.x};
                float* dsty[4] = {&ry0.x, &ry1.x, &ry2.x, &ry3.x};
#pragma unroll
                for (int it = 0; it < 4; ++it) {
                    const size_t base = (size_t)(mrw + (it << 4)) * GENES + d;
                    for (int q = 0; q < nq; ++q) {
                        dstx[it][q] = xb[base + q];
                        dsty[it][q] = yb[base + q];
                    }
                }
            }
        }
    };

    // ---- convert regs -> hi/lo bf16, write to LDS buffer ----
    auto convert_write = [&](int buf) {
        const int bofs = buf * NDS * KC;
        const float4 vx[4] = {rx0, rx1, rx2, rx3};
        const float4 vy[4] = {ry0, ry1, ry2, ry3};
#pragma unroll
        for (int it = 0; it < 4; ++it) {
            const int m = mrw + (it << 4);
            const float* px = &vx[it].x;
            const float* py = &vy[it].x;
            ushort4v xh, xl, yh, yl;
#pragma unroll
            for (int q = 0; q < 4; ++q) {
                const unsigned short h = f2bf(px[q]);
                xh[q] = h; xl[q] = f2bf(px[q] - bf2f(h));
                const unsigned short g = f2bf(py[q]);
                yh[q] = g; yl[q] = f2bf(py[q] - bf2f(g));
            }
            const int e = bofs + m * KC + (dcol ^ ((m & 7) << 3));
            *(ushort4v*)&sXh[e] = xh;
            *(ushort4v*)&sXl[e] = xl;
            *(ushort4v*)&sYh[e] = yh;
            *(ushort4v*)&sYl[e] = yl;
        }
    };

    const int nchunks = (d1 - d0 + KC - 1) / KC;

    // prologue: stage chunk 0 into buf 0
    issue_loads(d0);
    convert_write(0);

    for (int ci = 0; ci < nchunks; ++ci) {
        const int cur = ci & 1;
        const bool more = (ci + 1 < nchunks);
        if (more) issue_loads(d0 + (ci + 1) * KC);   // in flight across barrier+MFMA

        __syncthreads();   // buf[cur] writes visible; buf[cur^1] free to overwrite

        // ---- compute from buf[cur]: 4 K=16 steps, 9 MFMAs each ----
        const int bofs = cur * NDS * KC;
#pragma unroll
        for (int ks = 0; ks < 4; ++ks) {
            const int kb = (ks << 4) + kh;
            const int er = bofs + mr * KC + (kb ^ ((mr & 7) << 3));
            const int ec = bofs + mc * KC + (kb ^ ((mc & 7) << 3));
            const short8 xhr = *(const short8*)&sXh[er];
            const short8 xlr = *(const short8*)&sXl[er];
            const short8 yhr = *(const short8*)&sYh[er];
            const short8 ylr = *(const short8*)&sYl[er];
            const short8 xhc = *(const short8*)&sXh[ec];
            const short8 xlc = *(const short8*)&sXl[ec];
            const short8 yhc = *(const short8*)&sYh[ec];
            const short8 ylc = *(const short8*)&sYl[ec];
            axy = __builtin_amdgcn_mfma_f32_32x32x16_bf16(xhr, yhc, axy, 0, 0, 0);
            axx = __builtin_amdgcn_mfma_f32_32x32x16_bf16(xhr, xhc, axx, 0, 0, 0);
            ayy = __builtin_amdgcn_mfma_f32_32x32x16_bf16(yhr, yhc, ayy, 0, 0, 0);
            axy = __builtin_amdgcn_mfma_f32_32x32x16_bf16(xhr, ylc, axy, 0, 0, 0);
            axx = __builtin_amdgcn_mfma_f32_32x32x16_bf16(xhr, xlc, axx, 0, 0, 0);
            ayy = __builtin_amdgcn_mfma_f32_32x32x16_bf16(yhr, ylc, ayy, 0, 0, 0);
            axy = __builtin_amdgcn_mfma_f32_32x32x16_bf16(xlr, yhc, axy, 0, 0, 0);
            axx = __builtin_amdgcn_mfma_f32_32x32x16_bf16(xlr, xhc, axx, 0, 0, 0);
            ayy = __builtin_amdgcn_mfma_f32_32x32x16_bf16(ylr, yhc, ayy, 0, 0, 0);
        }

        // ---- late phase: drain loads, convert, write next buffer ----
        if (more) convert_write(cur ^ 1);
    }

    // ---- writeout: verified 32x32 C/D layout: col=lane&31,
    //      row=(reg&3)+8*(reg>>2)+4*(lane>>5) ----
    float* g = grams + (size_t)(b * splitD + c) * 3 * 4096;
    const int col = (qc << 5) + lm;
#pragma unroll
    for (int r = 0; r < 16; ++r) {
        const int row = (qr << 5) + (r & 3) + ((r >> 2) << 3) + ((lane >> 5) << 2);
        g[0 * 4096 + row * 64 + col] = axy[r];
        g[1 * 4096 + row * 64 + col] = axx[r];
        g[2 * 4096 + row * 64 + col] = ayy[r];
    }
}

// ---------------------------------------------------------------------------
// K2: per batch — reduce Gram partials, distances, mean, accumulate.
// ---------------------------------------------------------------------------
__global__ __launch_bounds__(256) void k_gene_dist(const float* __restrict__ grams,
                                                   float* __restrict__ acc,
                                                   int splitD) {
    const int b = blockIdx.x, t = threadIdx.x;
    __shared__ __align__(16) float G[3 * 4096];   // 48 KB
    __shared__ float red[4];

    for (int m = 0; m < 3; ++m) {
#pragma unroll
        for (int k = 0; k < 16; ++k) {
            const int e = t + 256 * k;
            float s = 0.f;
            for (int c = 0; c < splitD; ++c)
                s += grams[((size_t)(b * splitD + c) * 3 + m) * 4096 + e];
            G[m * 4096 + e] = s;
        }
    }
    __syncthreads();

    float local = 0.f;
#pragma unroll
    for (int k = 0; k < 16; ++k) {
        const int e = t + 256 * k;
        const int i = e >> 6, j = e & 63;
        const float gxy = G[e];
        const float gxx = G[4096 + e];
        const float gyy = G[8192 + e];
        const float nxi = G[4096 + i * 65], nxj = G[4096 + j * 65];
        const float nyi = G[8192 + i * 65], nyj = G[8192 + j * 65];
        const float dxy = sqrtf(fmaxf(nxi + nyj - 2.f * gxy, 0.f));
        const float dxx = sqrtf(fmaxf(nxi + nxj - 2.f * gxx, 0.f));
        const float dyy = sqrtf(fmaxf(nyi + nyj - 2.f * gyy, 0.f));
        local += dxy - 0.5f * (dxx + dyy);
    }
#pragma unroll
    for (int off = 32; off; off >>= 1) local += __shfl_down(local, off);
    if ((t & 63) == 0) red[t >> 6] = local;
    __syncthreads();
    if (t == 0) {
        const float bl = red[0] + red[1] + red[2] + red[3];
        atomicAdd(acc, bl * (1.0f / (4096.0f * (float)NB)));
    }
}

// ---------------------------------------------------------------------------
// K3: cell-level — one block per shared gene s. Clouds: 64 points x 128 dims.
// ---------------------------------------------------------------------------
__global__ __launch_bounds__(256) void k_cell(const float* __restrict__ X,
                                              const float* __restrict__ Y,
                                              float* __restrict__ acc) {
    const int s   = blockIdx.x;
    const int col = GENES - NSHARED + s;
    const int t   = threadIdx.x;

    // cx tile [b][n] at [0..8191], cy at [8192..16383]; reused for Grams after
    __shared__ __align__(16) float lds[16384];    // 64 KB

#pragma unroll
    for (int k = 0; k < 32; ++k) {
        const int idx = t + 256 * k;              // = b*64 + n, 0..8191
        lds[idx]        = X[(size_t)idx * GENES + col];
        lds[8192 + idx] = Y[(size_t)idx * GENES + col];
    }
    __syncthreads();

    const int ti = t & 15, tj = t >> 4;
    const int i0 = ti << 2, j0 = tj << 2;
    float axy[4][4] = {{0}}, axx[4][4] = {{0}}, ayy[4][4] = {{0}};

#pragma unroll 4
    for (int bb = 0; bb < NB; ++bb) {
        const float4 xi4 = *(const float4*)(lds + bb * 64 + i0);
        const float4 xj4 = *(const float4*)(lds + bb * 64 + j0);
        const float4 yi4 = *(const float4*)(lds + 8192 + bb * 64 + i0);
        const float4 yj4 = *(const float4*)(lds + 8192 + bb * 64 + j0);
        const float* xi = &xi4.x;
        const float* xj = &xj4.x;
        const float* yi = &yi4.x;
        const float* yj = &yj4.x;
#pragma unroll
        for (int ii = 0; ii < 4; ++ii) {
#pragma unroll
            for (int jj = 0; jj < 4; ++jj) {
                axy[ii][jj] = fmaf(xi[ii], yj[jj], axy[ii][jj]);
                axx[ii][jj] = fmaf(xi[ii], xj[jj], axx[ii][jj]);
                ayy[ii][jj] = fmaf(yi[ii], yj[jj], ayy[ii][jj]);
            }
        }
    }
    __syncthreads();
    // write Grams into lds[0..12287] (tiles no longer needed)
#pragma unroll
    for (int ii = 0; ii < 4; ++ii) {
        float4 v;
        v.x = axy[ii][0]; v.y = axy[ii][1]; v.z = axy[ii][2]; v.w = axy[ii][3];
        *(float4*)(lds + 0 * 4096 + (i0 + ii) * 64 + j0) = v;
        v.x = axx[ii][0]; v.y = axx[ii][1]; v.z = axx[ii][2]; v.w = axx[ii][3];
        *(float4*)(lds + 1 * 4096 + (i0 + ii) * 64 + j0) = v;
        v.x = ayy[ii][0]; v.y = ayy[ii][1]; v.z = ayy[ii][2]; v.w = ayy[ii][3];
        *(float4*)(lds + 2 * 4096 + (i0 + ii) * 64 + j0) = v;
    }
    __syncthreads();

    float local = 0.f;
#pragma unroll
    for (int k = 0; k < 16; ++k) {
        const int e = t + 256 * k;
        const int i = e >> 6, j = e & 63;
        const float gxy = lds[e];
        const float gxx = lds[4096 + e];
        const float gyy = lds[8192 + e];
        const float nxi = lds[4096 + i * 65], nxj = lds[4096 + j * 65];
        const float nyi = lds[8192 + i * 65], nyj = lds[8192 + j * 65];
        const float dxy = sqrtf(fmaxf(nxi + nyj - 2.f * gxy, 0.f));
        const float dxx = sqrtf(fmaxf(nxi + nxj - 2.f * gxx, 0.f));
        const float dyy = sqrtf(fmaxf(nyi + nyj - 2.f * gyy, 0.f));
        local += dxy - 0.5f * (dxx + dyy);
    }
#pragma unroll
    for (int off = 32; off; off >>= 1) local += __shfl_down(local, off);
    __syncthreads();                 // done reading lds as Grams
    if ((t & 63) == 0) lds[t >> 6] = local;
    __syncthreads();
    if (t == 0) {
        const float bl = lds[0] + lds[1] + lds[2] + lds[3];
        atomicAdd(acc, bl * (1.0f / (4096.0f * (float)NSHARED)));
    }
}

__global__ void k_final(const float* __restrict__ acc, float* __restrict__ out) {
    out[0] = acc[0] + acc[1];
}

extern "C" void kernel_launch(void* const* d_in, const int* in_sizes, int n_in,
                              void* d_out, int out_size, void* d_ws, size_t ws_size,
                              hipStream_t stream) {
    const float* X = (const float*)d_in[0];
    const float* Y = (const float*)d_in[1];
    float* out = (float*)d_out;
    float* ws  = (float*)d_ws;

    // splitD=4 (round-4 showed 8 only adds gram traffic, no occupancy win)
    int splitD = 4;
    while (splitD > 1 &&
           ((size_t)GRAM_OFF + (size_t)splitD * NB * 3 * 4096) * sizeof(float) > ws_size)
        splitD >>= 1;
    const int chunks = (GENES + KC - 1) / KC;            // 79
    const int cper   = (chunks + splitD - 1) / splitD;   // chunks per slice
    const int Dper   = cper * KC;                        // multiple of KC

    float* acc   = ws;
    float* grams = ws + GRAM_OFF;

    hipLaunchKernelGGL(k_zero,           dim3(1),           dim3(64),  0, stream, acc);
    hipLaunchKernelGGL(k_gene_gram_mfma, dim3(NB * splitD), dim3(256), 0, stream,
                       X, Y, grams, splitD, Dper);
    hipLaunchKernelGGL(k_gene_dist,      dim3(NB),          dim3(256), 0, stream,
                       grams, acc + 0, splitD);
    hipLaunchKernelGGL(k_cell,           dim3(NSHARED),     dim3(256), 0, stream,
                       X, Y, acc + 1);
    hipLaunchKernelGGL(k_final,          dim3(1),           dim3(1),   0, stream, acc, out);
}

// Round 6
// 206.222 us; speedup vs baseline: 1.2186x; 1.0923x over previous
//
#include <hip/hip_runtime.h>
#include <math.h>

#define TOTAL   8192
#define GENES   5000
#define NDS     64          // points per cloud
#define NB      128         // TOTAL / NDS
#define NSHARED 128
#define KC      64          // K-chunk staged in LDS

// ws layout (floats): [0]=gene acc, [1]=cell acc, grams start at GRAM_OFF
#define GRAM_OFF 64

typedef __attribute__((ext_vector_type(8)))  short          short8;
typedef __attribute__((ext_vector_type(4)))  unsigned short ushort4v;
typedef __attribute__((ext_vector_type(16))) float          f32x16;

static __device__ inline unsigned short f2bf(float f) {
    unsigned int u = __builtin_bit_cast(unsigned int, f);
    unsigned int r = (u + 0x7fffu + ((u >> 16) & 1u)) >> 16;   // RNE
    return (unsigned short)r;
}
static __device__ inline float bf2f(unsigned short h) {
    unsigned int u = ((unsigned int)h) << 16;
    return __builtin_bit_cast(float, u);
}

__global__ __launch_bounds__(64) void k_zero(float* ws) {
    ws[threadIdx.x] = 0.0f;
}

// ---------------------------------------------------------------------------
// K1: partial Gram matrices per (batch, K-slice) via bf16 hi/lo split MFMA.
// T14 async-stage: double-buffered LDS, ONE barrier per chunk; global loads
// issued into NAMED registers before the barrier (no address-taking anywhere,
// round-5's scratch-spill bug), consumed after the MFMA phase.
// Tail note: GENES, chunk starts, d1, dcol all %4==0 -> a float4 is always
// fully in-bounds or fully out; no partial path needed.
// grams[(b*splitD + c)][m][64*64], m: 0=xy, 1=xx, 2=yy
// ---------------------------------------------------------------------------
__global__ __launch_bounds__(256) void k_gene_gram_mfma(const float* __restrict__ X,
                                                        const float* __restrict__ Y,
                                                        float* __restrict__ grams,
                                                        int splitD, int Dper) {
    const int blk = blockIdx.x;
    const int b = blk / splitD, c = blk % splitD;
    const int d0 = c * Dper;
    const int d1 = min(GENES, d0 + Dper);

    const float* __restrict__ xb = X + (size_t)b * NDS * GENES;
    const float* __restrict__ yb = Y + (size_t)b * NDS * GENES;

    // [buf][m][k] bf16 tiles, element-XOR swizzle k ^ ((m&7)<<3) (16B blocks)
    __shared__ __align__(16) unsigned short sXh[2 * NDS * KC], sXl[2 * NDS * KC];
    __shared__ __align__(16) unsigned short sYh[2 * NDS * KC], sYl[2 * NDS * KC];

    const int t    = threadIdx.x;
    const int lane = t & 63;
    const int w    = t >> 6;               // wave 0..3
    const int qr   = w >> 1, qc = w & 1;   // 32x32 output quadrant
    const int lm   = lane & 31;
    const int kh   = (lane >> 5) << 3;     // k-half offset (same for A/B: cancels)

    const int mr = (qr << 5) + lm;         // A-side row
    const int mc = (qc << 5) + lm;         // B-side row (Gram col)

    // staging-thread geometry
    const int c4   = t & 15;               // float4 column within chunk
    const int mrw  = t >> 4;               // base row (16 rows per iteration)
    const int dcol = c4 << 2;

    f32x16 axy = {0,0,0,0,0,0,0,0,0,0,0,0,0,0,0,0};
    f32x16 axx = {0,0,0,0,0,0,0,0,0,0,0,0,0,0,0,0};
    f32x16 ayy = {0,0,0,0,0,0,0,0,0,0,0,0,0,0,0,0};

    float4 rx0, rx1, rx2, rx3, ry0, ry1, ry2, ry3;   // named; addresses never taken

    // ---- issue chunk loads into registers (all-or-nothing float4) ----
    auto issue_loads = [&](int dd0) {
        const int d = dd0 + dcol;
        if (d + 3 < d1) {
            const float* px = xb + (size_t)mrw * GENES + d;
            const float* py = yb + (size_t)mrw * GENES + d;
            rx0 = *(const float4*)(px);
            ry0 = *(const float4*)(py);
            rx1 = *(const float4*)(px + 16 * GENES);
            ry1 = *(const float4*)(py + 16 * GENES);
            rx2 = *(const float4*)(px + 32 * GENES);
            ry2 = *(const float4*)(py + 32 * GENES);
            rx3 = *(const float4*)(px + 48 * GENES);
            ry3 = *(const float4*)(py + 48 * GENES);
        } else {
            const float4 z = {0.f, 0.f, 0.f, 0.f};
            rx0 = rx1 = rx2 = rx3 = z;
            ry0 = ry1 = ry2 = ry3 = z;
        }
    };

    // float4 -> hi/lo bf16 (by value; vector-element writes, no references to regs)
    auto mk4 = [&](const float4 v, ushort4v& h, ushort4v& l) {
        unsigned short a;
        a = f2bf(v.x); h[0] = a; l[0] = f2bf(v.x - bf2f(a));
        a = f2bf(v.y); h[1] = a; l[1] = f2bf(v.y - bf2f(a));
        a = f2bf(v.z); h[2] = a; l[2] = f2bf(v.z - bf2f(a));
        a = f2bf(v.w); h[3] = a; l[3] = f2bf(v.w - bf2f(a));
    };
    auto put = [&](int it, const float4 vx, const float4 vy, int bofs) {
        const int m = mrw + (it << 4);
        ushort4v xh, xl, yh, yl;
        mk4(vx, xh, xl);
        mk4(vy, yh, yl);
        const int e = bofs + m * KC + (dcol ^ ((m & 7) << 3));
        *(ushort4v*)&sXh[e] = xh;
        *(ushort4v*)&sXl[e] = xl;
        *(ushort4v*)&sYh[e] = yh;
        *(ushort4v*)&sYl[e] = yl;
    };
    auto convert_write = [&](int buf) {
        const int bofs = buf * NDS * KC;
        put(0, rx0, ry0, bofs);
        put(1, rx1, ry1, bofs);
        put(2, rx2, ry2, bofs);
        put(3, rx3, ry3, bofs);
    };

    const int nchunks = (d1 - d0 + KC - 1) / KC;

    // prologue: stage chunk 0 into buf 0
    issue_loads(d0);
    convert_write(0);

    for (int ci = 0; ci < nchunks; ++ci) {
        const int cur = ci & 1;
        const bool more = (ci + 1 < nchunks);
        if (more) issue_loads(d0 + (ci + 1) * KC);   // in flight across barrier+MFMA

        __syncthreads();   // buf[cur] writes visible; buf[cur^1] free to overwrite

        // ---- compute from buf[cur]: 4 K=16 steps, 9 MFMAs each ----
        const int bofs = cur * NDS * KC;
#pragma unroll
        for (int ks = 0; ks < 4; ++ks) {
            const int kb = (ks << 4) + kh;
            const int er = bofs + mr * KC + (kb ^ ((mr & 7) << 3));
            const int ec = bofs + mc * KC + (kb ^ ((mc & 7) << 3));
            const short8 xhr = *(const short8*)&sXh[er];
            const short8 xlr = *(const short8*)&sXl[er];
            const short8 yhr = *(const short8*)&sYh[er];
            const short8 ylr = *(const short8*)&sYl[er];
            const short8 xhc = *(const short8*)&sXh[ec];
            const short8 xlc = *(const short8*)&sXl[ec];
            const short8 yhc = *(const short8*)&sYh[ec];
            const short8 ylc = *(const short8*)&sYl[ec];
            axy = __builtin_amdgcn_mfma_f32_32x32x16_bf16(xhr, yhc, axy, 0, 0, 0);
            axx = __builtin_amdgcn_mfma_f32_32x32x16_bf16(xhr, xhc, axx, 0, 0, 0);
            ayy = __builtin_amdgcn_mfma_f32_32x32x16_bf16(yhr, yhc, ayy, 0, 0, 0);
            axy = __builtin_amdgcn_mfma_f32_32x32x16_bf16(xhr, ylc, axy, 0, 0, 0);
            axx = __builtin_amdgcn_mfma_f32_32x32x16_bf16(xhr, xlc, axx, 0, 0, 0);
            ayy = __builtin_amdgcn_mfma_f32_32x32x16_bf16(yhr, ylc, ayy, 0, 0, 0);
            axy = __builtin_amdgcn_mfma_f32_32x32x16_bf16(xlr, yhc, axy, 0, 0, 0);
            axx = __builtin_amdgcn_mfma_f32_32x32x16_bf16(xlr, xhc, axx, 0, 0, 0);
            ayy = __builtin_amdgcn_mfma_f32_32x32x16_bf16(ylr, yhc, ayy, 0, 0, 0);
        }

        // ---- late phase: drain loads (vmcnt), convert, write next buffer ----
        if (more) convert_write(cur ^ 1);
    }

    // ---- writeout: verified 32x32 C/D layout: col=lane&31,
    //      row=(reg&3)+8*(reg>>2)+4*(lane>>5) ----
    float* g = grams + (size_t)(b * splitD + c) * 3 * 4096;
    const int col = (qc << 5) + lm;
#pragma unroll
    for (int r = 0; r < 16; ++r) {
        const int row = (qr << 5) + (r & 3) + ((r >> 2) << 3) + ((lane >> 5) << 2);
        g[0 * 4096 + row * 64 + col] = axy[r];
        g[1 * 4096 + row * 64 + col] = axx[r];
        g[2 * 4096 + row * 64 + col] = ayy[r];
    }
}

// ---------------------------------------------------------------------------
// K2: per batch — reduce Gram partials, distances, mean, accumulate.
// ---------------------------------------------------------------------------
__global__ __launch_bounds__(256) void k_gene_dist(const float* __restrict__ grams,
                                                   float* __restrict__ acc,
                                                   int splitD) {
    const int b = blockIdx.x, t = threadIdx.x;
    __shared__ __align__(16) float G[3 * 4096];   // 48 KB
    __shared__ float red[4];

    for (int m = 0; m < 3; ++m) {
#pragma unroll
        for (int k = 0; k < 16; ++k) {
            const int e = t + 256 * k;
            float s = 0.f;
            for (int c = 0; c < splitD; ++c)
                s += grams[((size_t)(b * splitD + c) * 3 + m) * 4096 + e];
            G[m * 4096 + e] = s;
        }
    }
    __syncthreads();

    float local = 0.f;
#pragma unroll
    for (int k = 0; k < 16; ++k) {
        const int e = t + 256 * k;
        const int i = e >> 6, j = e & 63;
        const float gxy = G[e];
        const float gxx = G[4096 + e];
        const float gyy = G[8192 + e];
        const float nxi = G[4096 + i * 65], nxj = G[4096 + j * 65];
        const float nyi = G[8192 + i * 65], nyj = G[8192 + j * 65];
        const float dxy = sqrtf(fmaxf(nxi + nyj - 2.f * gxy, 0.f));
        const float dxx = sqrtf(fmaxf(nxi + nxj - 2.f * gxx, 0.f));
        const float dyy = sqrtf(fmaxf(nyi + nyj - 2.f * gyy, 0.f));
        local += dxy - 0.5f * (dxx + dyy);
    }
#pragma unroll
    for (int off = 32; off; off >>= 1) local += __shfl_down(local, off);
    if ((t & 63) == 0) red[t >> 6] = local;
    __syncthreads();
    if (t == 0) {
        const float bl = red[0] + red[1] + red[2] + red[3];
        atomicAdd(acc, bl * (1.0f / (4096.0f * (float)NB)));
    }
}

// ---------------------------------------------------------------------------
// K3: cell-level — one block per shared gene s. Clouds: 64 points x 128 dims.
// ---------------------------------------------------------------------------
__global__ __launch_bounds__(256) void k_cell(const float* __restrict__ X,
                                              const float* __restrict__ Y,
                                              float* __restrict__ acc) {
    const int s   = blockIdx.x;
    const int col = GENES - NSHARED + s;
    const int t   = threadIdx.x;

    // cx tile [b][n] at [0..8191], cy at [8192..16383]; reused for Grams after
    __shared__ __align__(16) float lds[16384];    // 64 KB

#pragma unroll
    for (int k = 0; k < 32; ++k) {
        const int idx = t + 256 * k;              // = b*64 + n, 0..8191
        lds[idx]        = X[(size_t)idx * GENES + col];
        lds[8192 + idx] = Y[(size_t)idx * GENES + col];
    }
    __syncthreads();

    const int ti = t & 15, tj = t >> 4;
    const int i0 = ti << 2, j0 = tj << 2;
    float axy[4][4] = {{0}}, axx[4][4] = {{0}}, ayy[4][4] = {{0}};

#pragma unroll 4
    for (int bb = 0; bb < NB; ++bb) {
        const float4 xi4 = *(const float4*)(lds + bb * 64 + i0);
        const float4 xj4 = *(const float4*)(lds + bb * 64 + j0);
        const float4 yi4 = *(const float4*)(lds + 8192 + bb * 64 + i0);
        const float4 yj4 = *(const float4*)(lds + 8192 + bb * 64 + j0);
        const float* xi = &xi4.x;
        const float* xj = &xj4.x;
        const float* yi = &yi4.x;
        const float* yj = &yj4.x;
#pragma unroll
        for (int ii = 0; ii < 4; ++ii) {
#pragma unroll
            for (int jj = 0; jj < 4; ++jj) {
                axy[ii][jj] = fmaf(xi[ii], yj[jj], axy[ii][jj]);
                axx[ii][jj] = fmaf(xi[ii], xj[jj], axx[ii][jj]);
                ayy[ii][jj] = fmaf(yi[ii], yj[jj], ayy[ii][jj]);
            }
        }
    }
    __syncthreads();
    // write Grams into lds[0..12287] (tiles no longer needed)
#pragma unroll
    for (int ii = 0; ii < 4; ++ii) {
        float4 v;
        v.x = axy[ii][0]; v.y = axy[ii][1]; v.z = axy[ii][2]; v.w = axy[ii][3];
        *(float4*)(lds + 0 * 4096 + (i0 + ii) * 64 + j0) = v;
        v.x = axx[ii][0]; v.y = axx[ii][1]; v.z = axx[ii][2]; v.w = axx[ii][3];
        *(float4*)(lds + 1 * 4096 + (i0 + ii) * 64 + j0) = v;
        v.x = ayy[ii][0]; v.y = ayy[ii][1]; v.z = ayy[ii][2]; v.w = ayy[ii][3];
        *(float4*)(lds + 2 * 4096 + (i0 + ii) * 64 + j0) = v;
    }
    __syncthreads();

    float local = 0.f;
#pragma unroll
    for (int k = 0; k < 16; ++k) {
        const int e = t + 256 * k;
        const int i = e >> 6, j = e & 63;
        const float gxy = lds[e];
        const float gxx = lds[4096 + e];
        const float gyy = lds[8192 + e];
        const float nxi = lds[4096 + i * 65], nxj = lds[4096 + j * 65];
        const float nyi = lds[8192 + i * 65], nyj = lds[8192 + j * 65];
        const float dxy = sqrtf(fmaxf(nxi + nyj - 2.f * gxy, 0.f));
        const float dxx = sqrtf(fmaxf(nxi + nxj - 2.f * gxx, 0.f));
        const float dyy = sqrtf(fmaxf(nyi + nyj - 2.f * gyy, 0.f));
        local += dxy - 0.5f * (dxx + dyy);
    }
#pragma unroll
    for (int off = 32; off; off >>= 1) local += __shfl_down(local, off);
    __syncthreads();                 // done reading lds as Grams
    if ((t & 63) == 0) lds[t >> 6] = local;
    __syncthreads();
    if (t == 0) {
        const float bl = lds[0] + lds[1] + lds[2] + lds[3];
        atomicAdd(acc, bl * (1.0f / (4096.0f * (float)NSHARED)));
    }
}

__global__ void k_final(const float* __restrict__ acc, float* __restrict__ out) {
    out[0] = acc[0] + acc[1];
}

extern "C" void kernel_launch(void* const* d_in, const int* in_sizes, int n_in,
                              void* d_out, int out_size, void* d_ws, size_t ws_size,
                              hipStream_t stream) {
    const float* X = (const float*)d_in[0];
    const float* Y = (const float*)d_in[1];
    float* out = (float*)d_out;
    float* ws  = (float*)d_ws;

    // splitD=4 (round-4 showed 8 only adds gram traffic, no occupancy win)
    int splitD = 4;
    while (splitD > 1 &&
           ((size_t)GRAM_OFF + (size_t)splitD * NB * 3 * 4096) * sizeof(float) > ws_size)
        splitD >>= 1;
    const int chunks = (GENES + KC - 1) / KC;            // 79
    const int cper   = (chunks + splitD - 1) / splitD;   // chunks per slice
    const int Dper   = cper * KC;                        // multiple of KC

    float* acc   = ws;
    float* grams = ws + GRAM_OFF;

    hipLaunchKernelGGL(k_zero,           dim3(1),           dim3(64),  0, stream, acc);
    hipLaunchKernelGGL(k_gene_gram_mfma, dim3(NB * splitD), dim3(256), 0, stream,
                       X, Y, grams, splitD, Dper);
    hipLaunchKernelGGL(k_gene_dist,      dim3(NB),          dim3(256), 0, stream,
                       grams, acc + 0, splitD);
    hipLaunchKernelGGL(k_cell,           dim3(NSHARED),     dim3(256), 0, stream,
                       X, Y, acc + 1);
    hipLaunchKernelGGL(k_final,          dim3(1),           dim3(1),   0, stream, acc, out);
}

// Round 7
// 205.094 us; speedup vs baseline: 1.2253x; 1.0055x over previous
//
#include <hip/hip_runtime.h>
#include <math.h>

#define TOTAL   8192
#define GENES   5000
#define NDS     64          // points per cloud
#define NB      128         // TOTAL / NDS
#define NSHARED 128
#define KC      64          // K-chunk staged in LDS

// ws layout (floats): [0]=gene acc, [1]=cell acc, grams start at GRAM_OFF
#define GRAM_OFF 64

typedef __attribute__((ext_vector_type(8)))  short          short8;
typedef __attribute__((ext_vector_type(4)))  unsigned short ushort4v;
typedef __attribute__((ext_vector_type(16))) float          f32x16;

static __device__ inline unsigned short f2bf(float f) {
    unsigned int u = __builtin_bit_cast(unsigned int, f);
    unsigned int r = (u + 0x7fffu + ((u >> 16) & 1u)) >> 16;   // RNE
    return (unsigned short)r;
}
static __device__ inline float bf2f(unsigned short h) {
    unsigned int u = ((unsigned int)h) << 16;
    return __builtin_bit_cast(float, u);
}

__global__ __launch_bounds__(64) void k_zero(float* ws) {
    ws[threadIdx.x] = 0.0f;
}

// ---------------------------------------------------------------------------
// K1: partial Gram matrices per (batch, K-slice) via bf16 hi/lo split MFMA.
// T14/T4: double-buffered LDS, ONE raw barrier per chunk with NO vmcnt drain
// (plain __syncthreads() emits s_waitcnt vmcnt(0) before s_barrier — that
// drain was round-6's 28%-HBM duty cycle). Loads stay in flight across the
// barrier + MFMA phase; compiler's register-dep vmcnt(N) waits land at first
// use in convert_write. __launch_bounds__(256,2) raises the VGPR cap so the
// prefetch regs are NOT spilled (round-6: 88 VGPRs -> 100 MB scratch traffic).
// grams[(b*splitD + c)][m][64*64], m: 0=xy, 1=xx, 2=yy
// ---------------------------------------------------------------------------
__global__ __launch_bounds__(256, 2) void k_gene_gram_mfma(const float* __restrict__ X,
                                                           const float* __restrict__ Y,
                                                           float* __restrict__ grams,
                                                           int splitD, int Dper) {
    const int blk = blockIdx.x;
    const int b = blk / splitD, c = blk % splitD;
    const int d0 = c * Dper;
    const int d1 = min(GENES, d0 + Dper);

    const float* __restrict__ xb = X + (size_t)b * NDS * GENES;
    const float* __restrict__ yb = Y + (size_t)b * NDS * GENES;

    // [buf][m][k] bf16 tiles, element-XOR swizzle k ^ ((m&7)<<3) (16B blocks)
    __shared__ __align__(16) unsigned short sXh[2 * NDS * KC], sXl[2 * NDS * KC];
    __shared__ __align__(16) unsigned short sYh[2 * NDS * KC], sYl[2 * NDS * KC];

    const int t    = threadIdx.x;
    const int lane = t & 63;
    const int w    = t >> 6;               // wave 0..3
    const int qr   = w >> 1, qc = w & 1;   // 32x32 output quadrant
    const int lm   = lane & 31;
    const int kh   = (lane >> 5) << 3;     // k-half offset (same for A/B: cancels)

    const int mr = (qr << 5) + lm;         // A-side row
    const int mc = (qc << 5) + lm;         // B-side row (Gram col)

    // staging-thread geometry
    const int c4   = t & 15;               // float4 column within chunk
    const int mrw  = t >> 4;               // base row (16 rows per iteration)
    const int dcol = c4 << 2;

    f32x16 axy = {0,0,0,0,0,0,0,0,0,0,0,0,0,0,0,0};
    f32x16 axx = {0,0,0,0,0,0,0,0,0,0,0,0,0,0,0,0};
    f32x16 ayy = {0,0,0,0,0,0,0,0,0,0,0,0,0,0,0,0};

    float4 rx0, rx1, rx2, rx3, ry0, ry1, ry2, ry3;   // named; addresses never taken

    // ---- issue chunk loads into registers (all-or-nothing float4:
    //      GENES, chunk starts, dcol all %4==0) ----
    auto issue_loads = [&](int dd0) {
        const int d = dd0 + dcol;
        if (d + 3 < d1) {
            const float* px = xb + (size_t)mrw * GENES + d;
            const float* py = yb + (size_t)mrw * GENES + d;
            rx0 = *(const float4*)(px);
            ry0 = *(const float4*)(py);
            rx1 = *(const float4*)(px + 16 * GENES);
            ry1 = *(const float4*)(py + 16 * GENES);
            rx2 = *(const float4*)(px + 32 * GENES);
            ry2 = *(const float4*)(py + 32 * GENES);
            rx3 = *(const float4*)(px + 48 * GENES);
            ry3 = *(const float4*)(py + 48 * GENES);
        } else {
            const float4 z = {0.f, 0.f, 0.f, 0.f};
            rx0 = rx1 = rx2 = rx3 = z;
            ry0 = ry1 = ry2 = ry3 = z;
        }
    };

    // float4 -> hi/lo bf16 (by value; vector-element writes)
    auto mk4 = [&](const float4 v, ushort4v& h, ushort4v& l) {
        unsigned short a;
        a = f2bf(v.x); h[0] = a; l[0] = f2bf(v.x - bf2f(a));
        a = f2bf(v.y); h[1] = a; l[1] = f2bf(v.y - bf2f(a));
        a = f2bf(v.z); h[2] = a; l[2] = f2bf(v.z - bf2f(a));
        a = f2bf(v.w); h[3] = a; l[3] = f2bf(v.w - bf2f(a));
    };
    auto put = [&](int it, const float4 vx, const float4 vy, int bofs) {
        const int m = mrw + (it << 4);
        ushort4v xh, xl, yh, yl;
        mk4(vx, xh, xl);
        mk4(vy, yh, yl);
        const int e = bofs + m * KC + (dcol ^ ((m & 7) << 3));
        *(ushort4v*)&sXh[e] = xh;
        *(ushort4v*)&sXl[e] = xl;
        *(ushort4v*)&sYh[e] = yh;
        *(ushort4v*)&sYl[e] = yl;
    };
    auto convert_write = [&](int buf) {
        const int bofs = buf * NDS * KC;
        put(0, rx0, ry0, bofs);
        put(1, rx1, ry1, bofs);
        put(2, rx2, ry2, bofs);
        put(3, rx3, ry3, bofs);
    };

    const int nchunks = (d1 - d0 + KC - 1) / KC;

    // prologue: stage chunk 0 into buf 0 (vmcnt drain here is fine)
    issue_loads(d0);
    convert_write(0);

    for (int ci = 0; ci < nchunks; ++ci) {
        const int cur = ci & 1;
        const bool more = (ci + 1 < nchunks);
        if (more) issue_loads(d0 + (ci + 1) * KC);
        // pin the loads above this point, then barrier WITHOUT vmcnt drain
        __builtin_amdgcn_sched_barrier(0);
        asm volatile("s_waitcnt lgkmcnt(0)" ::: "memory");
        __builtin_amdgcn_s_barrier();

        // ---- compute from buf[cur]: 4 K=16 steps, 9 MFMAs each ----
        const int bofs = cur * NDS * KC;
#pragma unroll
        for (int ks = 0; ks < 4; ++ks) {
            const int kb = (ks << 4) + kh;
            const int er = bofs + mr * KC + (kb ^ ((mr & 7) << 3));
            const int ec = bofs + mc * KC + (kb ^ ((mc & 7) << 3));
            const short8 xhr = *(const short8*)&sXh[er];
            const short8 xlr = *(const short8*)&sXl[er];
            const short8 yhr = *(const short8*)&sYh[er];
            const short8 ylr = *(const short8*)&sYl[er];
            const short8 xhc = *(const short8*)&sXh[ec];
            const short8 xlc = *(const short8*)&sXl[ec];
            const short8 yhc = *(const short8*)&sYh[ec];
            const short8 ylc = *(const short8*)&sYl[ec];
            axy = __builtin_amdgcn_mfma_f32_32x32x16_bf16(xhr, yhc, axy, 0, 0, 0);
            axx = __builtin_amdgcn_mfma_f32_32x32x16_bf16(xhr, xhc, axx, 0, 0, 0);
            ayy = __builtin_amdgcn_mfma_f32_32x32x16_bf16(yhr, yhc, ayy, 0, 0, 0);
            axy = __builtin_amdgcn_mfma_f32_32x32x16_bf16(xhr, ylc, axy, 0, 0, 0);
            axx = __builtin_amdgcn_mfma_f32_32x32x16_bf16(xhr, xlc, axx, 0, 0, 0);
            ayy = __builtin_amdgcn_mfma_f32_32x32x16_bf16(yhr, ylc, ayy, 0, 0, 0);
            axy = __builtin_amdgcn_mfma_f32_32x32x16_bf16(xlr, yhc, axy, 0, 0, 0);
            axx = __builtin_amdgcn_mfma_f32_32x32x16_bf16(xlr, xhc, axx, 0, 0, 0);
            ayy = __builtin_amdgcn_mfma_f32_32x32x16_bf16(ylr, yhc, ayy, 0, 0, 0);
        }

        // ---- late phase: vmcnt waits land here (first use), convert, write ----
        if (more) convert_write(cur ^ 1);
    }

    // ---- writeout: verified 32x32 C/D layout: col=lane&31,
    //      row=(reg&3)+8*(reg>>2)+4*(lane>>5) ----
    float* g = grams + (size_t)(b * splitD + c) * 3 * 4096;
    const int col = (qc << 5) + lm;
#pragma unroll
    for (int r = 0; r < 16; ++r) {
        const int row = (qr << 5) + (r & 3) + ((r >> 2) << 3) + ((lane >> 5) << 2);
        g[0 * 4096 + row * 64 + col] = axy[r];
        g[1 * 4096 + row * 64 + col] = axx[r];
        g[2 * 4096 + row * 64 + col] = ayy[r];
    }
}

// ---------------------------------------------------------------------------
// K2: per batch — reduce Gram partials, distances, mean, accumulate.
// ---------------------------------------------------------------------------
__global__ __launch_bounds__(256) void k_gene_dist(const float* __restrict__ grams,
                                                   float* __restrict__ acc,
                                                   int splitD) {
    const int b = blockIdx.x, t = threadIdx.x;
    __shared__ __align__(16) float G[3 * 4096];   // 48 KB
    __shared__ float red[4];

    for (int m = 0; m < 3; ++m) {
#pragma unroll
        for (int k = 0; k < 16; ++k) {
            const int e = t + 256 * k;
            float s = 0.f;
            for (int c = 0; c < splitD; ++c)
                s += grams[((size_t)(b * splitD + c) * 3 + m) * 4096 + e];
            G[m * 4096 + e] = s;
        }
    }
    __syncthreads();

    float local = 0.f;
#pragma unroll
    for (int k = 0; k < 16; ++k) {
        const int e = t + 256 * k;
        const int i = e >> 6, j = e & 63;
        const float gxy = G[e];
        const float gxx = G[4096 + e];
        const float gyy = G[8192 + e];
        const float nxi = G[4096 + i * 65], nxj = G[4096 + j * 65];
        const float nyi = G[8192 + i * 65], nyj = G[8192 + j * 65];
        const float dxy = sqrtf(fmaxf(nxi + nyj - 2.f * gxy, 0.f));
        const float dxx = sqrtf(fmaxf(nxi + nxj - 2.f * gxx, 0.f));
        const float dyy = sqrtf(fmaxf(nyi + nyj - 2.f * gyy, 0.f));
        local += dxy - 0.5f * (dxx + dyy);
    }
#pragma unroll
    for (int off = 32; off; off >>= 1) local += __shfl_down(local, off);
    if ((t & 63) == 0) red[t >> 6] = local;
    __syncthreads();
    if (t == 0) {
        const float bl = red[0] + red[1] + red[2] + red[3];
        atomicAdd(acc, bl * (1.0f / (4096.0f * (float)NB)));
    }
}

// ---------------------------------------------------------------------------
// K3: cell-level — one block per shared gene s. Clouds: 64 points x 128 dims.
// ---------------------------------------------------------------------------
__global__ __launch_bounds__(256) void k_cell(const float* __restrict__ X,
                                              const float* __restrict__ Y,
                                              float* __restrict__ acc) {
    const int s   = blockIdx.x;
    const int col = GENES - NSHARED + s;
    const int t   = threadIdx.x;

    // cx tile [b][n] at [0..8191], cy at [8192..16383]; reused for Grams after
    __shared__ __align__(16) float lds[16384];    // 64 KB

#pragma unroll
    for (int k = 0; k < 32; ++k) {
        const int idx = t + 256 * k;              // = b*64 + n, 0..8191
        lds[idx]        = X[(size_t)idx * GENES + col];
        lds[8192 + idx] = Y[(size_t)idx * GENES + col];
    }
    __syncthreads();

    const int ti = t & 15, tj = t >> 4;
    const int i0 = ti << 2, j0 = tj << 2;
    float axy[4][4] = {{0}}, axx[4][4] = {{0}}, ayy[4][4] = {{0}};

#pragma unroll 4
    for (int bb = 0; bb < NB; ++bb) {
        const float4 xi4 = *(const float4*)(lds + bb * 64 + i0);
        const float4 xj4 = *(const float4*)(lds + bb * 64 + j0);
        const float4 yi4 = *(const float4*)(lds + 8192 + bb * 64 + i0);
        const float4 yj4 = *(const float4*)(lds + 8192 + bb * 64 + j0);
        const float* xi = &xi4.x;
        const float* xj = &xj4.x;
        const float* yi = &yi4.x;
        const float* yj = &yj4.x;
#pragma unroll
        for (int ii = 0; ii < 4; ++ii) {
#pragma unroll
            for (int jj = 0; jj < 4; ++jj) {
                axy[ii][jj] = fmaf(xi[ii], yj[jj], axy[ii][jj]);
                axx[ii][jj] = fmaf(xi[ii], xj[jj], axx[ii][jj]);
                ayy[ii][jj] = fmaf(yi[ii], yj[jj], ayy[ii][jj]);
            }
        }
    }
    __syncthreads();
    // write Grams into lds[0..12287] (tiles no longer needed)
#pragma unroll
    for (int ii = 0; ii < 4; ++ii) {
        float4 v;
        v.x = axy[ii][0]; v.y = axy[ii][1]; v.z = axy[ii][2]; v.w = axy[ii][3];
        *(float4*)(lds + 0 * 4096 + (i0 + ii) * 64 + j0) = v;
        v.x = axx[ii][0]; v.y = axx[ii][1]; v.z = axx[ii][2]; v.w = axx[ii][3];
        *(float4*)(lds + 1 * 4096 + (i0 + ii) * 64 + j0) = v;
        v.x = ayy[ii][0]; v.y = ayy[ii][1]; v.z = ayy[ii][2]; v.w = ayy[ii][3];
        *(float4*)(lds + 2 * 4096 + (i0 + ii) * 64 + j0) = v;
    }
    __syncthreads();

    float local = 0.f;
#pragma unroll
    for (int k = 0; k < 16; ++k) {
        const int e = t + 256 * k;
        const int i = e >> 6, j = e & 63;
        const float gxy = lds[e];
        const float gxx = lds[4096 + e];
        const float gyy = lds[8192 + e];
        const float nxi = lds[4096 + i * 65], nxj = lds[4096 + j * 65];
        const float nyi = lds[8192 + i * 65], nyj = lds[8192 + j * 65];
        const float dxy = sqrtf(fmaxf(nxi + nyj - 2.f * gxy, 0.f));
        const float dxx = sqrtf(fmaxf(nxi + nxj - 2.f * gxx, 0.f));
        const float dyy = sqrtf(fmaxf(nyi + nyj - 2.f * gyy, 0.f));
        local += dxy - 0.5f * (dxx + dyy);
    }
#pragma unroll
    for (int off = 32; off; off >>= 1) local += __shfl_down(local, off);
    __syncthreads();                 // done reading lds as Grams
    if ((t & 63) == 0) lds[t >> 6] = local;
    __syncthreads();
    if (t == 0) {
        const float bl = lds[0] + lds[1] + lds[2] + lds[3];
        atomicAdd(acc, bl * (1.0f / (4096.0f * (float)NSHARED)));
    }
}

__global__ void k_final(const float* __restrict__ acc, float* __restrict__ out) {
    out[0] = acc[0] + acc[1];
}

extern "C" void kernel_launch(void* const* d_in, const int* in_sizes, int n_in,
                              void* d_out, int out_size, void* d_ws, size_t ws_size,
                              hipStream_t stream) {
    const float* X = (const float*)d_in[0];
    const float* Y = (const float*)d_in[1];
    float* out = (float*)d_out;
    float* ws  = (float*)d_ws;

    // splitD=4 (round-4 showed 8 only adds gram traffic, no occupancy win)
    int splitD = 4;
    while (splitD > 1 &&
           ((size_t)GRAM_OFF + (size_t)splitD * NB * 3 * 4096) * sizeof(float) > ws_size)
        splitD >>= 1;
    const int chunks = (GENES + KC - 1) / KC;            // 79
    const int cper   = (chunks + splitD - 1) / splitD;   // chunks per slice
    const int Dper   = cper * KC;                        // multiple of KC

    float* acc   = ws;
    float* grams = ws + GRAM_OFF;

    hipLaunchKernelGGL(k_zero,           dim3(1),           dim3(64),  0, stream, acc);
    hipLaunchKernelGGL(k_gene_gram_mfma, dim3(NB * splitD), dim3(256), 0, stream,
                       X, Y, grams, splitD, Dper);
    hipLaunchKernelGGL(k_gene_dist,      dim3(NB),          dim3(256), 0, stream,
                       grams, acc + 0, splitD);
    hipLaunchKernelGGL(k_cell,           dim3(NSHARED),     dim3(256), 0, stream,
                       X, Y, acc + 1);
    hipLaunchKernelGGL(k_final,          dim3(1),           dim3(1),   0, stream, acc, out);
}

// Round 8
// 183.626 us; speedup vs baseline: 1.3686x; 1.1169x over previous
//
#include <hip/hip_runtime.h>
#include <math.h>

#define TOTAL   8192
#define GENES   5000
#define NDS     64          // points per cloud
#define NB      128         // TOTAL / NDS
#define NSHARED 128
#define KC      64          // K-chunk staged in LDS

// ws layout (floats): [0]=gene acc, [1]=cell acc, [32..35]=zero pad for tail,
// grams start at GRAM_OFF
#define GRAM_OFF 64

typedef __attribute__((ext_vector_type(8)))  short        short8;
typedef __attribute__((ext_vector_type(4)))  unsigned int uint4v;
typedef __attribute__((ext_vector_type(16))) float        f32x16;

typedef const __attribute__((address_space(1))) void* GPTR;
typedef __attribute__((address_space(3))) void*       LPTR;

// DMA global->LDS, 16B per lane, no VGPR transit (spill-proof staging)
#define GLOAD16(gp, lp) \
    __builtin_amdgcn_global_load_lds((GPTR)(gp), (LPTR)(lp), 16, 0, 0)

__global__ __launch_bounds__(64) void k_zero(float* ws) {
    ws[threadIdx.x] = 0.0f;
}

// ---- bf16 hi/lo split via truncation (lo compensates hi's rounding exactly;
//      residual |lo| <= 2^-8|f|, truncated lo error ~2^-16|f| -> negligible) ----
static __device__ inline unsigned int hpack(float f0, float f1) {
    const unsigned int u0 = __builtin_bit_cast(unsigned int, f0);
    const unsigned int u1 = __builtin_bit_cast(unsigned int, f1);
    return (u1 & 0xFFFF0000u) | (u0 >> 16);
}
static __device__ inline float tbf(float f) {
    return __builtin_bit_cast(float,
        __builtin_bit_cast(unsigned int, f) & 0xFFFF0000u);
}
struct HL8 { short8 h; short8 l; };
// read 8 consecutive logical fp32 (two 16B slots, XOR-swizzled) -> hi/lo bf16x8
static __device__ inline HL8 ldcvt(const float* base, int sw, int c0) {
    const float4 a = *(const float4*)(base + (((c0    ) ^ sw) << 2));
    const float4 b = *(const float4*)(base + (((c0 + 1) ^ sw) << 2));
    uint4v hv, lv;
    hv[0] = hpack(a.x, a.y); hv[1] = hpack(a.z, a.w);
    hv[2] = hpack(b.x, b.y); hv[3] = hpack(b.z, b.w);
    lv[0] = hpack(a.x - tbf(a.x), a.y - tbf(a.y));
    lv[1] = hpack(a.z - tbf(a.z), a.w - tbf(a.w));
    lv[2] = hpack(b.x - tbf(b.x), b.y - tbf(b.y));
    lv[3] = hpack(b.z - tbf(b.z), b.w - tbf(b.w));
    HL8 r;
    r.h = __builtin_bit_cast(short8, hv);
    r.l = __builtin_bit_cast(short8, lv);
    return r;
}

// ---------------------------------------------------------------------------
// K1: partial Grams per (batch, K-slice). Staging = global_load_lds DMA of raw
// fp32 (double-buffered, source-preswizzled blocks: slot s holds logical block
// s ^ (row&15)); convert-on-read to bf16 hi/lo; 9 MFMAs per K=16 step.
// Schedule: T3 2-phase — STAGE(next) issued BEFORE compute, ONE syncthreads
// per chunk, loads in flight across the whole MFMA phase.
// grams[(b*splitD + c)][m][64*64], m: 0=xy, 1=xx, 2=yy
// ---------------------------------------------------------------------------
__global__ __launch_bounds__(256, 2)
void k_gene_gram_mfma(const float* __restrict__ X, const float* __restrict__ Y,
                      const float* __restrict__ zsrc,
                      float* __restrict__ grams, int splitD, int Dper) {
    const int blk = blockIdx.x;
    const int b = blk / splitD, c = blk % splitD;
    const int d0 = c * Dper;
    const int d1 = min(GENES, d0 + Dper);

    const float* __restrict__ xb = X + (size_t)b * NDS * GENES;
    const float* __restrict__ yb = Y + (size_t)b * NDS * GENES;

    __shared__ __align__(16) float sX[2 * NDS * KC];   // 32 KB raw fp32
    __shared__ __align__(16) float sY[2 * NDS * KC];   // 32 KB

    const int t    = threadIdx.x;
    const int lane = t & 63;
    const int w    = t >> 6;               // wave 0..3
    const int qr   = w >> 1, qc = w & 1;   // 32x32 output quadrant
    const int lm   = lane & 31;
    const int kh2  = (lane >> 5) << 1;     // k-half offset in 16B slots (0 / 2)

    const int mr  = (qr << 5) + lm;        // A-side row
    const int mc  = (qc << 5) + lm;        // B-side row (Gram col)
    const int swr = mr & 15, swc = mc & 15;

    // ---- staging geometry: wave w stages rows [16w,16w+16), 4 instrs each ----
    const int s16  = lane & 15;            // 16B slot this lane fills
    const int rsub = lane >> 4;            // row within 4-row group
    const int rA = (w << 4) + rsub;
    const int rB = rA + 4, rC = rA + 8, rD = rA + 12;
    // pre-swizzled source column (floats; add chunk base dd at use)
    const int cA = (s16 ^ (rA & 15)) << 2;
    const int cB = (s16 ^ (rB & 15)) << 2;
    const int cC = (s16 ^ (rC & 15)) << 2;
    const int cD = (s16 ^ (rD & 15)) << 2;
    const float* gxA = xb + (size_t)rA * GENES + cA;
    const float* gxB = xb + (size_t)rB * GENES + cB;
    const float* gxC = xb + (size_t)rC * GENES + cC;
    const float* gxD = xb + (size_t)rD * GENES + cD;
    const float* gyA = yb + (size_t)rA * GENES + cA;
    const float* gyB = yb + (size_t)rB * GENES + cB;
    const float* gyC = yb + (size_t)rC * GENES + cC;
    const float* gyD = yb + (size_t)rD * GENES + cD;
    // uniform LDS float offsets (instruction bases; HW adds lane*16B)
    const int lA = ((w << 4) + 0) * KC;
    const int lB = lA + 4 * KC, lC = lA + 8 * KC, lD = lA + 12 * KC;

#define STAGEBUF(bofs, dd) do {                                               \
    const float* pxA = ((dd) + cA + 4 <= d1) ? gxA + (dd) : zsrc;             \
    const float* pxB = ((dd) + cB + 4 <= d1) ? gxB + (dd) : zsrc;             \
    const float* pxC = ((dd) + cC + 4 <= d1) ? gxC + (dd) : zsrc;             \
    const float* pxD = ((dd) + cD + 4 <= d1) ? gxD + (dd) : zsrc;             \
    const float* pyA = ((dd) + cA + 4 <= d1) ? gyA + (dd) : zsrc;             \
    const float* pyB = ((dd) + cB + 4 <= d1) ? gyB + (dd) : zsrc;             \
    const float* pyC = ((dd) + cC + 4 <= d1) ? gyC + (dd) : zsrc;             \
    const float* pyD = ((dd) + cD + 4 <= d1) ? gyD + (dd) : zsrc;             \
    GLOAD16(pxA, sX + (bofs) + lA);                                           \
    GLOAD16(pxB, sX + (bofs) + lB);                                           \
    GLOAD16(pxC, sX + (bofs) + lC);                                           \
    GLOAD16(pxD, sX + (bofs) + lD);                                           \
    GLOAD16(pyA, sY + (bofs) + lA);                                           \
    GLOAD16(pyB, sY + (bofs) + lB);                                           \
    GLOAD16(pyC, sY + (bofs) + lC);                                           \
    GLOAD16(pyD, sY + (bofs) + lD);                                           \
} while (0)

    f32x16 axy = {0,0,0,0,0,0,0,0,0,0,0,0,0,0,0,0};
    f32x16 axx = {0,0,0,0,0,0,0,0,0,0,0,0,0,0,0,0};
    f32x16 ayy = {0,0,0,0,0,0,0,0,0,0,0,0,0,0,0,0};

    const int nchunks = (d1 - d0 + KC - 1) / KC;

    STAGEBUF(0, d0);          // prologue: chunk 0 -> buf 0
    __syncthreads();          // vmcnt(0) + barrier: buf 0 ready

    for (int ci = 0; ci < nchunks; ++ci) {
        const int bofs = (ci & 1) * (NDS * KC);
        if (ci + 1 < nchunks)
            STAGEBUF(((ci + 1) & 1) * (NDS * KC), d0 + (ci + 1) * KC);

        const float* xrow = sX + bofs + mr * KC;
        const float* yrow = sY + bofs + mr * KC;
        const float* xcol = sX + bofs + mc * KC;
        const float* ycol = sY + bofs + mc * KC;
#pragma unroll
        for (int ks = 0; ks < 4; ++ks) {
            const int c0 = (ks << 2) + kh2;
            const HL8 xr = ldcvt(xrow, swr, c0);
            const HL8 yr = ldcvt(yrow, swr, c0);
            const HL8 xc = ldcvt(xcol, swc, c0);
            const HL8 yc = ldcvt(ycol, swc, c0);
            axy = __builtin_amdgcn_mfma_f32_32x32x16_bf16(xr.h, yc.h, axy, 0, 0, 0);
            axx = __builtin_amdgcn_mfma_f32_32x32x16_bf16(xr.h, xc.h, axx, 0, 0, 0);
            ayy = __builtin_amdgcn_mfma_f32_32x32x16_bf16(yr.h, yc.h, ayy, 0, 0, 0);
            axy = __builtin_amdgcn_mfma_f32_32x32x16_bf16(xr.h, yc.l, axy, 0, 0, 0);
            axx = __builtin_amdgcn_mfma_f32_32x32x16_bf16(xr.h, xc.l, axx, 0, 0, 0);
            ayy = __builtin_amdgcn_mfma_f32_32x32x16_bf16(yr.h, yc.l, ayy, 0, 0, 0);
            axy = __builtin_amdgcn_mfma_f32_32x32x16_bf16(xr.l, yc.h, axy, 0, 0, 0);
            axx = __builtin_amdgcn_mfma_f32_32x32x16_bf16(xr.l, xc.h, axx, 0, 0, 0);
            ayy = __builtin_amdgcn_mfma_f32_32x32x16_bf16(yr.l, yc.h, ayy, 0, 0, 0);
        }
        __syncthreads();      // drains stage loads (vmcnt 0) + buffer handoff
    }
#undef STAGEBUF

    // ---- writeout: verified 32x32 C/D layout: col=lane&31,
    //      row=(reg&3)+8*(reg>>2)+4*(lane>>5) ----
    float* g = grams + (size_t)(b * splitD + c) * 3 * 4096;
    const int col = (qc << 5) + lm;
#pragma unroll
    for (int r = 0; r < 16; ++r) {
        const int row = (qr << 5) + (r & 3) + ((r >> 2) << 3) + ((lane >> 5) << 2);
        g[0 * 4096 + row * 64 + col] = axy[r];
        g[1 * 4096 + row * 64 + col] = axx[r];
        g[2 * 4096 + row * 64 + col] = ayy[r];
    }
}

// ---------------------------------------------------------------------------
// K2: per batch — reduce Gram partials, distances, mean, accumulate.
// ---------------------------------------------------------------------------
__global__ __launch_bounds__(256) void k_gene_dist(const float* __restrict__ grams,
                                                   float* __restrict__ acc,
                                                   int splitD) {
    const int b = blockIdx.x, t = threadIdx.x;
    __shared__ __align__(16) float G[3 * 4096];   // 48 KB
    __shared__ float red[4];

    for (int m = 0; m < 3; ++m) {
#pragma unroll
        for (int k = 0; k < 16; ++k) {
            const int e = t + 256 * k;
            float s = 0.f;
            for (int c = 0; c < splitD; ++c)
                s += grams[((size_t)(b * splitD + c) * 3 + m) * 4096 + e];
            G[m * 4096 + e] = s;
        }
    }
    __syncthreads();

    float local = 0.f;
#pragma unroll
    for (int k = 0; k < 16; ++k) {
        const int e = t + 256 * k;
        const int i = e >> 6, j = e & 63;
        const float gxy = G[e];
        const float gxx = G[4096 + e];
        const float gyy = G[8192 + e];
        const float nxi = G[4096 + i * 65], nxj = G[4096 + j * 65];
        const float nyi = G[8192 + i * 65], nyj = G[8192 + j * 65];
        const float dxy = sqrtf(fmaxf(nxi + nyj - 2.f * gxy, 0.f));
        const float dxx = sqrtf(fmaxf(nxi + nxj - 2.f * gxx, 0.f));
        const float dyy = sqrtf(fmaxf(nyi + nyj - 2.f * gyy, 0.f));
        local += dxy - 0.5f * (dxx + dyy);
    }
#pragma unroll
    for (int off = 32; off; off >>= 1) local += __shfl_down(local, off);
    if ((t & 63) == 0) red[t >> 6] = local;
    __syncthreads();
    if (t == 0) {
        const float bl = red[0] + red[1] + red[2] + red[3];
        atomicAdd(acc, bl * (1.0f / (4096.0f * (float)NB)));
    }
}

// ---------------------------------------------------------------------------
// K3: cell-level — one block per shared gene s. Clouds: 64 points x 128 dims.
// ---------------------------------------------------------------------------
__global__ __launch_bounds__(256) void k_cell(const float* __restrict__ X,
                                              const float* __restrict__ Y,
                                              float* __restrict__ acc) {
    const int s   = blockIdx.x;
    const int col = GENES - NSHARED + s;
    const int t   = threadIdx.x;

    __shared__ __align__(16) float lds[16384];    // 64 KB

#pragma unroll
    for (int k = 0; k < 32; ++k) {
        const int idx = t + 256 * k;              // = b*64 + n, 0..8191
        lds[idx]        = X[(size_t)idx * GENES + col];
        lds[8192 + idx] = Y[(size_t)idx * GENES + col];
    }
    __syncthreads();

    const int ti = t & 15, tj = t >> 4;
    const int i0 = ti << 2, j0 = tj << 2;
    float axy[4][4] = {{0}}, axx[4][4] = {{0}}, ayy[4][4] = {{0}};

#pragma unroll 4
    for (int bb = 0; bb < NB; ++bb) {
        const float4 xi4 = *(const float4*)(lds + bb * 64 + i0);
        const float4 xj4 = *(const float4*)(lds + bb * 64 + j0);
        const float4 yi4 = *(const float4*)(lds + 8192 + bb * 64 + i0);
        const float4 yj4 = *(const float4*)(lds + 8192 + bb * 64 + j0);
        const float* xi = &xi4.x;
        const float* xj = &xj4.x;
        const float* yi = &yi4.x;
        const float* yj = &yj4.x;
#pragma unroll
        for (int ii = 0; ii < 4; ++ii) {
#pragma unroll
            for (int jj = 0; jj < 4; ++jj) {
                axy[ii][jj] = fmaf(xi[ii], yj[jj], axy[ii][jj]);
                axx[ii][jj] = fmaf(xi[ii], xj[jj], axx[ii][jj]);
                ayy[ii][jj] = fmaf(yi[ii], yj[jj], ayy[ii][jj]);
            }
        }
    }
    __syncthreads();
#pragma unroll
    for (int ii = 0; ii < 4; ++ii) {
        float4 v;
        v.x = axy[ii][0]; v.y = axy[ii][1]; v.z = axy[ii][2]; v.w = axy[ii][3];
        *(float4*)(lds + 0 * 4096 + (i0 + ii) * 64 + j0) = v;
        v.x = axx[ii][0]; v.y = axx[ii][1]; v.z = axx[ii][2]; v.w = axx[ii][3];
        *(float4*)(lds + 1 * 4096 + (i0 + ii) * 64 + j0) = v;
        v.x = ayy[ii][0]; v.y = ayy[ii][1]; v.z = ayy[ii][2]; v.w = ayy[ii][3];
        *(float4*)(lds + 2 * 4096 + (i0 + ii) * 64 + j0) = v;
    }
    __syncthreads();

    float local = 0.f;
#pragma unroll
    for (int k = 0; k < 16; ++k) {
        const int e = t + 256 * k;
        const int i = e >> 6, j = e & 63;
        const float gxy = lds[e];
        const float gxx = lds[4096 + e];
        const float gyy = lds[8192 + e];
        const float nxi = lds[4096 + i * 65], nxj = lds[4096 + j * 65];
        const float nyi = lds[8192 + i * 65], nyj = lds[8192 + j * 65];
        const float dxy = sqrtf(fmaxf(nxi + nyj - 2.f * gxy, 0.f));
        const float dxx = sqrtf(fmaxf(nxi + nxj - 2.f * gxx, 0.f));
        const float dyy = sqrtf(fmaxf(nyi + nyj - 2.f * gyy, 0.f));
        local += dxy - 0.5f * (dxx + dyy);
    }
#pragma unroll
    for (int off = 32; off; off >>= 1) local += __shfl_down(local, off);
    __syncthreads();
    if ((t & 63) == 0) lds[t >> 6] = local;
    __syncthreads();
    if (t == 0) {
        const float bl = lds[0] + lds[1] + lds[2] + lds[3];
        atomicAdd(acc, bl * (1.0f / (4096.0f * (float)NSHARED)));
    }
}

__global__ void k_final(const float* __restrict__ acc, float* __restrict__ out) {
    out[0] = acc[0] + acc[1];
}

extern "C" void kernel_launch(void* const* d_in, const int* in_sizes, int n_in,
                              void* d_out, int out_size, void* d_ws, size_t ws_size,
                              hipStream_t stream) {
    const float* X = (const float*)d_in[0];
    const float* Y = (const float*)d_in[1];
    float* out = (float*)d_out;
    float* ws  = (float*)d_ws;

    int splitD = 4;
    while (splitD > 1 &&
           ((size_t)GRAM_OFF + (size_t)splitD * NB * 3 * 4096) * sizeof(float) > ws_size)
        splitD >>= 1;
    const int chunks = (GENES + KC - 1) / KC;            // 79
    const int cper   = (chunks + splitD - 1) / splitD;   // chunks per slice
    const int Dper   = cper * KC;                        // multiple of KC

    float* acc   = ws;
    float* zsrc  = ws + 32;          // 16B of zeros (k_zero covers [0,64))
    float* grams = ws + GRAM_OFF;

    hipLaunchKernelGGL(k_zero,           dim3(1),           dim3(64),  0, stream, ws);
    hipLaunchKernelGGL(k_gene_gram_mfma, dim3(NB * splitD), dim3(256), 0, stream,
                       X, Y, zsrc, grams, splitD, Dper);
    hipLaunchKernelGGL(k_gene_dist,      dim3(NB),          dim3(256), 0, stream,
                       grams, acc + 0, splitD);
    hipLaunchKernelGGL(k_cell,           dim3(NSHARED),     dim3(256), 0, stream,
                       X, Y, acc + 1);
    hipLaunchKernelGGL(k_final,          dim3(1),           dim3(1),   0, stream, acc, out);
}

// Round 9
// 161.807 us; speedup vs baseline: 1.5531x; 1.1348x over previous
//
#include <hip/hip_runtime.h>
#include <math.h>

#define TOTAL   8192
#define GENES   5000
#define NDS     64          // points per cloud
#define NB      128         // TOTAL / NDS
#define NSHARED 128
#define KC      64          // K-chunk staged in LDS

// ws layout (floats): [0]=gene acc, [1]=cell acc, [32..35]=zero pad for tail,
// grams start at GRAM_OFF
#define GRAM_OFF 64

typedef __attribute__((ext_vector_type(8)))  short        short8;
typedef __attribute__((ext_vector_type(4)))  unsigned int uint4v;
typedef __attribute__((ext_vector_type(16))) float        f32x16;

typedef const __attribute__((address_space(1))) void* GPTR;
typedef __attribute__((address_space(3))) void*       LPTR;

// DMA global->LDS, 16B per lane, no VGPR transit (spill-proof staging)
#define GLOAD16(gp, lp) \
    __builtin_amdgcn_global_load_lds((GPTR)(gp), (LPTR)(lp), 16, 0, 0)

__global__ __launch_bounds__(64) void k_zero(float* ws) {
    ws[threadIdx.x] = 0.0f;
}

// ---- fp32 -> bf16 round-half-up (E[err]~0: no systematic norm bias; the
//      energy-distance structure cancels first-order bias anyway), packed
//      pairwise. hh-only MFMA: per-Gram-entry err std ~0.1 on O(1e4) entries
//      -> final loss err ~1e-3 vs 3.6e-2 threshold. ----
static __device__ inline unsigned int hpack2(float f0, float f1) {
    const unsigned int u0 = __builtin_bit_cast(unsigned int, f0) + 0x8000u;
    const unsigned int u1 = __builtin_bit_cast(unsigned int, f1) + 0x8000u;
    return (u1 & 0xFFFF0000u) | (u0 >> 16);
}
// read 8 consecutive logical fp32 (two 16B slots, XOR-swizzled) -> bf16x8
static __device__ inline short8 ldcvt_h(const float* base, int sw, int c0) {
    const float4 a = *(const float4*)(base + (((c0    ) ^ sw) << 2));
    const float4 b = *(const float4*)(base + (((c0 + 1) ^ sw) << 2));
    uint4v hv;
    hv[0] = hpack2(a.x, a.y); hv[1] = hpack2(a.z, a.w);
    hv[2] = hpack2(b.x, b.y); hv[3] = hpack2(b.z, b.w);
    return __builtin_bit_cast(short8, hv);
}

// ---------------------------------------------------------------------------
// K1: partial Grams per (batch, K-slice). Staging = global_load_lds DMA of raw
// fp32 (double-buffered, source-preswizzled blocks: slot s holds logical block
// s ^ (row&15)); convert-on-read to bf16 (round-half-up); 3 MFMAs per K=16.
// Schedule: T3 2-phase — STAGE(next) issued BEFORE compute, ONE syncthreads
// per chunk, loads in flight across the whole MFMA phase.
// grams[(b*splitD + c)][m][64*64], m: 0=xy, 1=xx, 2=yy
// ---------------------------------------------------------------------------
__global__ __launch_bounds__(256, 2)
void k_gene_gram_mfma(const float* __restrict__ X, const float* __restrict__ Y,
                      const float* __restrict__ zsrc,
                      float* __restrict__ grams, int splitD, int Dper) {
    const int blk = blockIdx.x;
    const int b = blk / splitD, c = blk % splitD;
    const int d0 = c * Dper;
    const int d1 = min(GENES, d0 + Dper);

    const float* __restrict__ xb = X + (size_t)b * NDS * GENES;
    const float* __restrict__ yb = Y + (size_t)b * NDS * GENES;

    __shared__ __align__(16) float sX[2 * NDS * KC];   // 32 KB raw fp32
    __shared__ __align__(16) float sY[2 * NDS * KC];   // 32 KB

    const int t    = threadIdx.x;
    const int lane = t & 63;
    const int w    = t >> 6;               // wave 0..3
    const int qr   = w >> 1, qc = w & 1;   // 32x32 output quadrant
    const int lm   = lane & 31;
    const int kh2  = (lane >> 5) << 1;     // k-half offset in 16B slots (0 / 2)

    const int mr  = (qr << 5) + lm;        // A-side row
    const int mc  = (qc << 5) + lm;        // B-side row (Gram col)
    const int swr = mr & 15, swc = mc & 15;

    // ---- staging geometry: wave w stages rows [16w,16w+16), 4 instrs each ----
    const int s16  = lane & 15;            // 16B slot this lane fills
    const int rsub = lane >> 4;            // row within 4-row group
    const int rA = (w << 4) + rsub;
    const int rB = rA + 4, rC = rA + 8, rD = rA + 12;
    // pre-swizzled source column (floats; add chunk base dd at use)
    const int cA = (s16 ^ (rA & 15)) << 2;
    const int cB = (s16 ^ (rB & 15)) << 2;
    const int cC = (s16 ^ (rC & 15)) << 2;
    const int cD = (s16 ^ (rD & 15)) << 2;
    const float* gxA = xb + (size_t)rA * GENES + cA;
    const float* gxB = xb + (size_t)rB * GENES + cB;
    const float* gxC = xb + (size_t)rC * GENES + cC;
    const float* gxD = xb + (size_t)rD * GENES + cD;
    const float* gyA = yb + (size_t)rA * GENES + cA;
    const float* gyB = yb + (size_t)rB * GENES + cB;
    const float* gyC = yb + (size_t)rC * GENES + cC;
    const float* gyD = yb + (size_t)rD * GENES + cD;
    // uniform LDS float offsets (instruction bases; HW adds lane*16B)
    const int lA = ((w << 4) + 0) * KC;
    const int lB = lA + 4 * KC, lC = lA + 8 * KC, lD = lA + 12 * KC;

#define STAGEBUF(bofs, dd) do {                                               \
    const float* pxA = ((dd) + cA + 4 <= d1) ? gxA + (dd) : zsrc;             \
    const float* pxB = ((dd) + cB + 4 <= d1) ? gxB + (dd) : zsrc;             \
    const float* pxC = ((dd) + cC + 4 <= d1) ? gxC + (dd) : zsrc;             \
    const float* pxD = ((dd) + cD + 4 <= d1) ? gxD + (dd) : zsrc;             \
    const float* pyA = ((dd) + cA + 4 <= d1) ? gyA + (dd) : zsrc;             \
    const float* pyB = ((dd) + cB + 4 <= d1) ? gyB + (dd) : zsrc;             \
    const float* pyC = ((dd) + cC + 4 <= d1) ? gyC + (dd) : zsrc;             \
    const float* pyD = ((dd) + cD + 4 <= d1) ? gyD + (dd) : zsrc;             \
    GLOAD16(pxA, sX + (bofs) + lA);                                           \
    GLOAD16(pxB, sX + (bofs) + lB);                                           \
    GLOAD16(pxC, sX + (bofs) + lC);                                           \
    GLOAD16(pxD, sX + (bofs) + lD);                                           \
    GLOAD16(pyA, sY + (bofs) + lA);                                           \
    GLOAD16(pyB, sY + (bofs) + lB);                                           \
    GLOAD16(pyC, sY + (bofs) + lC);                                           \
    GLOAD16(pyD, sY + (bofs) + lD);                                           \
} while (0)

    f32x16 axy = {0,0,0,0,0,0,0,0,0,0,0,0,0,0,0,0};
    f32x16 axx = {0,0,0,0,0,0,0,0,0,0,0,0,0,0,0,0};
    f32x16 ayy = {0,0,0,0,0,0,0,0,0,0,0,0,0,0,0,0};

    const int nchunks = (d1 - d0 + KC - 1) / KC;

    STAGEBUF(0, d0);          // prologue: chunk 0 -> buf 0
    __syncthreads();          // vmcnt(0) + barrier: buf 0 ready

    for (int ci = 0; ci < nchunks; ++ci) {
        const int bofs = (ci & 1) * (NDS * KC);
        if (ci + 1 < nchunks)
            STAGEBUF(((ci + 1) & 1) * (NDS * KC), d0 + (ci + 1) * KC);

        const float* xrow = sX + bofs + mr * KC;
        const float* yrow = sY + bofs + mr * KC;
        const float* xcol = sX + bofs + mc * KC;
        const float* ycol = sY + bofs + mc * KC;
#pragma unroll
        for (int ks = 0; ks < 4; ++ks) {
            const int c0 = (ks << 2) + kh2;
            const short8 xr = ldcvt_h(xrow, swr, c0);
            const short8 yr = ldcvt_h(yrow, swr, c0);
            const short8 xc = ldcvt_h(xcol, swc, c0);
            const short8 yc = ldcvt_h(ycol, swc, c0);
            axy = __builtin_amdgcn_mfma_f32_32x32x16_bf16(xr, yc, axy, 0, 0, 0);
            axx = __builtin_amdgcn_mfma_f32_32x32x16_bf16(xr, xc, axx, 0, 0, 0);
            ayy = __builtin_amdgcn_mfma_f32_32x32x16_bf16(yr, yc, ayy, 0, 0, 0);
        }
        __syncthreads();      // drains stage loads (vmcnt 0) + buffer handoff
    }
#undef STAGEBUF

    // ---- writeout: verified 32x32 C/D layout: col=lane&31,
    //      row=(reg&3)+8*(reg>>2)+4*(lane>>5) ----
    float* g = grams + (size_t)(b * splitD + c) * 3 * 4096;
    const int col = (qc << 5) + lm;
#pragma unroll
    for (int r = 0; r < 16; ++r) {
        const int row = (qr << 5) + (r & 3) + ((r >> 2) << 3) + ((lane >> 5) << 2);
        g[0 * 4096 + row * 64 + col] = axy[r];
        g[1 * 4096 + row * 64 + col] = axx[r];
        g[2 * 4096 + row * 64 + col] = ayy[r];
    }
}

// ---------------------------------------------------------------------------
// K2: per batch — reduce Gram partials, distances, mean, accumulate.
// ---------------------------------------------------------------------------
__global__ __launch_bounds__(256) void k_gene_dist(const float* __restrict__ grams,
                                                   float* __restrict__ acc,
                                                   int splitD) {
    const int b = blockIdx.x, t = threadIdx.x;
    __shared__ __align__(16) float G[3 * 4096];   // 48 KB
    __shared__ float red[4];

    for (int m = 0; m < 3; ++m) {
#pragma unroll
        for (int k = 0; k < 16; ++k) {
            const int e = t + 256 * k;
            float s = 0.f;
            for (int c = 0; c < splitD; ++c)
                s += grams[((size_t)(b * splitD + c) * 3 + m) * 4096 + e];
            G[m * 4096 + e] = s;
        }
    }
    __syncthreads();

    float local = 0.f;
#pragma unroll
    for (int k = 0; k < 16; ++k) {
        const int e = t + 256 * k;
        const int i = e >> 6, j = e & 63;
        const float gxy = G[e];
        const float gxx = G[4096 + e];
        const float gyy = G[8192 + e];
        const float nxi = G[4096 + i * 65], nxj = G[4096 + j * 65];
        const float nyi = G[8192 + i * 65], nyj = G[8192 + j * 65];
        const float dxy = sqrtf(fmaxf(nxi + nyj - 2.f * gxy, 0.f));
        const float dxx = sqrtf(fmaxf(nxi + nxj - 2.f * gxx, 0.f));
        const float dyy = sqrtf(fmaxf(nyi + nyj - 2.f * gyy, 0.f));
        local += dxy - 0.5f * (dxx + dyy);
    }
#pragma unroll
    for (int off = 32; off; off >>= 1) local += __shfl_down(local, off);
    if ((t & 63) == 0) red[t >> 6] = local;
    __syncthreads();
    if (t == 0) {
        const float bl = red[0] + red[1] + red[2] + red[3];
        atomicAdd(acc, bl * (1.0f / (4096.0f * (float)NB)));
    }
}

// ---------------------------------------------------------------------------
// K3: cell-level — one block per shared gene s. Clouds: 64 points x 128 dims.
// fp32 vector-FMA path (exact).
// ---------------------------------------------------------------------------
__global__ __launch_bounds__(256) void k_cell(const float* __restrict__ X,
                                              const float* __restrict__ Y,
                                              float* __restrict__ acc) {
    const int s   = blockIdx.x;
    const int col = GENES - NSHARED + s;
    const int t   = threadIdx.x;

    __shared__ __align__(16) float lds[16384];    // 64 KB

#pragma unroll
    for (int k = 0; k < 32; ++k) {
        const int idx = t + 256 * k;              // = b*64 + n, 0..8191
        lds[idx]        = X[(size_t)idx * GENES + col];
        lds[8192 + idx] = Y[(size_t)idx * GENES + col];
    }
    __syncthreads();

    const int ti = t & 15, tj = t >> 4;
    const int i0 = ti << 2, j0 = tj << 2;
    float axy[4][4] = {{0}}, axx[4][4] = {{0}}, ayy[4][4] = {{0}};

#pragma unroll 4
    for (int bb = 0; bb < NB; ++bb) {
        const float4 xi4 = *(const float4*)(lds + bb * 64 + i0);
        const float4 xj4 = *(const float4*)(lds + bb * 64 + j0);
        const float4 yi4 = *(const float4*)(lds + 8192 + bb * 64 + i0);
        const float4 yj4 = *(const float4*)(lds + 8192 + bb * 64 + j0);
        const float* xi = &xi4.x;
        const float* xj = &xj4.x;
        const float* yi = &yi4.x;
        const float* yj = &yj4.x;
#pragma unroll
        for (int ii = 0; ii < 4; ++ii) {
#pragma unroll
            for (int jj = 0; jj < 4; ++jj) {
                axy[ii][jj] = fmaf(xi[ii], yj[jj], axy[ii][jj]);
                axx[ii][jj] = fmaf(xi[ii], xj[jj], axx[ii][jj]);
                ayy[ii][jj] = fmaf(yi[ii], yj[jj], ayy[ii][jj]);
            }
        }
    }
    __syncthreads();
#pragma unroll
    for (int ii = 0; ii < 4; ++ii) {
        float4 v;
        v.x = axy[ii][0]; v.y = axy[ii][1]; v.z = axy[ii][2]; v.w = axy[ii][3];
        *(float4*)(lds + 0 * 4096 + (i0 + ii) * 64 + j0) = v;
        v.x = axx[ii][0]; v.y = axx[ii][1]; v.z = axx[ii][2]; v.w = axx[ii][3];
        *(float4*)(lds + 1 * 4096 + (i0 + ii) * 64 + j0) = v;
        v.x = ayy[ii][0]; v.y = ayy[ii][1]; v.z = ayy[ii][2]; v.w = ayy[ii][3];
        *(float4*)(lds + 2 * 4096 + (i0 + ii) * 64 + j0) = v;
    }
    __syncthreads();

    float local = 0.f;
#pragma unroll
    for (int k = 0; k < 16; ++k) {
        const int e = t + 256 * k;
        const int i = e >> 6, j = e & 63;
        const float gxy = lds[e];
        const float gxx = lds[4096 + e];
        const float gyy = lds[8192 + e];
        const float nxi = lds[4096 + i * 65], nxj = lds[4096 + j * 65];
        const float nyi = lds[8192 + i * 65], nyj = lds[8192 + j * 65];
        const float dxy = sqrtf(fmaxf(nxi + nyj - 2.f * gxy, 0.f));
        const float dxx = sqrtf(fmaxf(nxi + nxj - 2.f * gxx, 0.f));
        const float dyy = sqrtf(fmaxf(nyi + nyj - 2.f * gyy, 0.f));
        local += dxy - 0.5f * (dxx + dyy);
    }
#pragma unroll
    for (int off = 32; off; off >>= 1) local += __shfl_down(local, off);
    __syncthreads();
    if ((t & 63) == 0) lds[t >> 6] = local;
    __syncthreads();
    if (t == 0) {
        const float bl = lds[0] + lds[1] + lds[2] + lds[3];
        atomicAdd(acc, bl * (1.0f / (4096.0f * (float)NSHARED)));
    }
}

__global__ void k_final(const float* __restrict__ acc, float* __restrict__ out) {
    out[0] = acc[0] + acc[1];
}

extern "C" void kernel_launch(void* const* d_in, const int* in_sizes, int n_in,
                              void* d_out, int out_size, void* d_ws, size_t ws_size,
                              hipStream_t stream) {
    const float* X = (const float*)d_in[0];
    const float* Y = (const float*)d_in[1];
    float* out = (float*)d_out;
    float* ws  = (float*)d_ws;

    int splitD = 4;
    while (splitD > 1 &&
           ((size_t)GRAM_OFF + (size_t)splitD * NB * 3 * 4096) * sizeof(float) > ws_size)
        splitD >>= 1;
    const int chunks = (GENES + KC - 1) / KC;            // 79
    const int cper   = (chunks + splitD - 1) / splitD;   // chunks per slice
    const int Dper   = cper * KC;                        // multiple of KC

    float* acc   = ws;
    float* zsrc  = ws + 32;          // 16B of zeros (k_zero covers [0,64))
    float* grams = ws + GRAM_OFF;

    hipLaunchKernelGGL(k_zero,           dim3(1),           dim3(64),  0, stream, ws);
    hipLaunchKernelGGL(k_gene_gram_mfma, dim3(NB * splitD), dim3(256), 0, stream,
                       X, Y, zsrc, grams, splitD, Dper);
    hipLaunchKernelGGL(k_gene_dist,      dim3(NB),          dim3(256), 0, stream,
                       grams, acc + 0, splitD);
    hipLaunchKernelGGL(k_cell,           dim3(NSHARED),     dim3(256), 0, stream,
                       X, Y, acc + 1);
    hipLaunchKernelGGL(k_final,          dim3(1),           dim3(1),   0, stream, acc, out);
}